// Round 1
// baseline (549.925 us; speedup 1.0000x reference)
//
#include <hip/hip_runtime.h>
#include <math.h>

#define N_NODES 10000
#define N_EDGES 160000
#define G_SEG 16
#define ZDIM 10
#define KDIM 64
#define NBESS 8
#define HIDR 16
#define RMAXF 5.0f
#define AVG_NEI_F 16.0f
#define TBINS 1024

__device__ __forceinline__ float siluf(float x){ float s = 1.0f/(1.0f+expf(-x)); return x*s; }
__device__ __forceinline__ float dsiluf(float x){ float s = 1.0f/(1.0f+expf(-x)); return s*(1.0f + x*(1.0f-s)); }

__device__ __forceinline__ float waveReduce(float v){
  for (int off = 32; off > 0; off >>= 1) v += __shfl_down(v, off);
  return v;
}

// ---------------- small precompute: folded layer-0 node tensors + transposes ----------------
__global__ __launch_bounds__(256) void k_prep(
    const float* We, const float* Wup, const float* Wsc,
    const float* Wout, const float* Wmix,
    float* M0, float* Msc0,
    float* WoT0, float* WoT1, float* WmixT0, float* WmixT1,
    float* WupT1, float* WscT1){
  int tid = threadIdx.x;
  int j = tid & 63, q = tid >> 6; // q in 0..3
  for (int z = q; z < ZDIM; z += 4){
    float m0 = 0.f, ms = 0.f;
    for (int k = 0; k < KDIM; k++){
      float f = We[z*KDIM + k];
      m0 += f * Wup[k*KDIM + j];                 // W_up[0]
      ms += f * Wsc[(z*KDIM + k)*KDIM + j];      // W_sc[0,z]
    }
    M0[z*KDIM + j] = m0; Msc0[z*KDIM + j] = ms;
  }
  for (int k = q*16; k < q*16+16; k++){
    WoT0[j*KDIM + k]   = Wout[k*KDIM + j];                      // W_out[0,0]^T
    WoT1[j*KDIM + k]   = Wout[3*KDIM*KDIM + k*KDIM + j];        // W_out[1,0]^T
    WmixT0[j*KDIM + k] = Wmix[k*KDIM + j];
    WmixT1[j*KDIM + k] = Wmix[KDIM*KDIM + k*KDIM + j];
    WupT1[j*KDIM + k]  = Wup[KDIM*KDIM + k*KDIM + j];
  }
  for (int z = 0; z < ZDIM; z++)
    for (int k = q*16; k < q*16+16; k++)
      WscT1[(z*KDIM + j)*KDIM + k] = Wsc[((ZDIM + z)*KDIM + k)*KDIM + j]; // W_sc[1,z]^T
}

__global__ __launch_bounds__(256) void k_node_init(const float* attrs, const float* aE,
                                                   int* z_buf, float* e_node){
  int n = blockIdx.x*256 + threadIdx.x;
  if (n >= N_NODES) return;
  int z = 0;
  for (int i = 1; i < ZDIM; i++) if (attrs[n*ZDIM+i] > 0.5f) z = i;
  z_buf[n] = z;
  e_node[n] = aE[z];
}

__global__ __launch_bounds__(256) void k_h0(const int* z_buf, const float* M0, float* h0){
  int idx = blockIdx.x*256 + threadIdx.x;
  int n = idx >> 6, j = idx & 63;
  h0[idx] = M0[z_buf[n]*KDIM + j];
}

__global__ __launch_bounds__(256) void k_edge_setup(const float* pos, const float* shifts, const int* ei,
                                                    float* r_buf, float* vx, float* vy, float* vz){
  int e = blockIdx.x*256 + threadIdx.x;
  int s = ei[e], rcv = ei[N_EDGES + e];
  float dx = pos[rcv*3+0] - pos[s*3+0] + shifts[e*3+0];
  float dy = pos[rcv*3+1] - pos[s*3+1] + shifts[e*3+1];
  float dz = pos[rcv*3+2] - pos[s*3+2] + shifts[e*3+2];
  float r = sqrtf(dx*dx + dy*dy + dz*dz + 1e-9f);
  r_buf[e] = r; vx[e] = dx; vy[e] = dy; vz[e] = dz;
}

__global__ __launch_bounds__(256) void k_count(const int* ei, int* cnt_r, int* cnt_s){
  int e = blockIdx.x*256 + threadIdx.x;
  atomicAdd(&cnt_s[ei[e]], 1);
  atomicAdd(&cnt_r[ei[N_EDGES + e]], 1);
}

__global__ __launch_bounds__(1024) void k_scan(const int* cnt_r, int* ptr_r, int* cur_r,
                                               const int* cnt_s, int* ptr_s, int* cur_s){
  __shared__ int part[1024];
  int tid = threadIdx.x;
  for (int pass = 0; pass < 2; pass++){
    const int* cnt = pass ? cnt_s : cnt_r;
    int* ptr = pass ? ptr_s : ptr_r;
    int* cur = pass ? cur_s : cur_r;
    const int per = 10; // 10*1024 >= N
    int start = tid*per;
    int s = 0;
    for (int t = 0; t < per; t++){ int i = start + t; if (i < N_NODES) s += cnt[i]; }
    part[tid] = s; __syncthreads();
    for (int d = 1; d < 1024; d <<= 1){
      int v = (tid >= d) ? part[tid-d] : 0;
      __syncthreads();
      part[tid] += v;
      __syncthreads();
    }
    int run = part[tid] - s; // exclusive prefix
    for (int t = 0; t < per; t++){
      int i = start + t;
      if (i < N_NODES){ ptr[i] = run; cur[i] = run; run += cnt[i]; }
    }
    if (tid == 1023) ptr[N_NODES] = part[1023];
    __syncthreads();
  }
}

__global__ __launch_bounds__(256) void k_fill(const int* ei, int* cur_r, int* cur_s,
                                              int* eid_r, int* eid_s){
  int e = blockIdx.x*256 + threadIdx.x;
  int p = atomicAdd(&cur_s[ei[e]], 1); eid_s[p] = e;
  int p2 = atomicAdd(&cur_r[ei[N_EDGES + e]], 1); eid_r[p2] = e;
}

// ---------------- radial-MLP table: F_i(r) and F_i'(r), both layers ----------------
__global__ __launch_bounds__(64) void k_table(const float* R1g, const float* R2g,
                                              const float* R3g, const float* R4g,
                                              float* Ftab0, float* Ftab1, float* dF0, float* dF1){
  int t = blockIdx.x, j = threadIdx.x;
  __shared__ float efs[NBESS], defs[NBESS];
  __shared__ float xs[KDIM], dxs[KDIM];
  if (j < NBESS){
    double r = (double)t * (double)RMAXF / (double)TBINS;
    double w = (double)(j+1) * M_PI / (double)RMAXF;
    double c = sqrt(2.0 / (double)RMAXF);
    double bess, dbess;
    if (r < 1e-12){ bess = c*w; dbess = 0.0; }
    else {
      double sw = sin(w*r), cw = cos(w*r);
      bess = c*sw/r;
      dbess = c*(w*cw*r - sw)/(r*r);
    }
    double xx = r / (double)RMAXF;
    double f = 0.0, df = 0.0;
    if (xx < 1.0){
      double x2 = xx*xx, x4 = x2*x2, x5 = x4*xx, x6 = x5*xx, x7 = x6*xx;
      f = 1.0 - 21.0*x5 + 35.0*x6 - 15.0*x7;
      df = (-105.0*x4 + 210.0*x5 - 105.0*x6) / (double)RMAXF;
    }
    efs[j]  = (float)(bess*f);
    defs[j] = (float)(dbess*f + bess*df);
  }
  __syncthreads();
  for (int i = 0; i < 2; i++){
    const float* R1 = R1g + i*NBESS*KDIM;
    const float* R2 = R2g + i*KDIM*KDIM;
    const float* R3 = R3g + i*KDIM*KDIM;
    const float* R4 = R4g + i*KDIM*KDIM;
    float z = 0.f, dz = 0.f;
    for (int b = 0; b < NBESS; b++){ float w = R1[b*KDIM+j]; z += efs[b]*w; dz += defs[b]*w; }
    float v = siluf(z), dv = dsiluf(z)*dz;
    xs[j] = v; dxs[j] = dv; __syncthreads();
    z = 0.f; dz = 0.f;
    for (int k = 0; k < KDIM; k++){ float w = R2[k*KDIM+j]; z += xs[k]*w; dz += dxs[k]*w; }
    v = siluf(z); dv = dsiluf(z)*dz; __syncthreads();
    xs[j] = v; dxs[j] = dv; __syncthreads();
    z = 0.f; dz = 0.f;
    for (int k = 0; k < KDIM; k++){ float w = R3[k*KDIM+j]; z += xs[k]*w; dz += dxs[k]*w; }
    v = siluf(z); dv = dsiluf(z)*dz; __syncthreads();
    xs[j] = v; dxs[j] = dv; __syncthreads();
    z = 0.f; dz = 0.f;
    for (int k = 0; k < KDIM; k++){ float w = R4[k*KDIM+j]; z += xs[k]*w; dz += dxs[k]*w; }
    float* Ft  = i ? Ftab1 : Ftab0;
    float* dFt = i ? dF1 : dF0;
    Ft[t*KDIM+j] = z; dFt[t*KDIM+j] = dz;
    __syncthreads();
  }
}

// ---------------- fused per-node forward layer (wave per node, lane = k) ----------------
__global__ __launch_bounds__(256) void k_layer_fwd(int layer,
    const int* z_buf, const int* ptr_r, const int* eid_r, const int* ei,
    const float* r_buf, const float* Ftab, const float* hsrc,
    const float* Wout_l0, const float* theta_l, const float* Wmix_l,
    const float* Msc0, const float* sc1,
    const float* w_read0, const float* Wr1, const float* Wr2,
    float* A0_out, float* feats_out, float* t_hid, float* e_node){
  __shared__ float lds[4][KDIM];
  int tid = threadIdx.x;
  int w = tid >> 6, lane = tid & 63;
  int node = blockIdx.x*4 + w;
  int z = z_buf[node];
  float acc = 0.f;
  int beg = ptr_r[node], end = ptr_r[node+1];
  for (int idx = beg; idx < end; idx++){
    int e = eid_r[idx];
    float r = r_buf[e];
    if (r < RMAXF){
      float tp = r * (TBINS / RMAXF);
      int b = (int)tp; if (b > TBINS-1) b = TBINS-1;
      float fr = tp - (float)b;
      float f0 = Ftab[b*KDIM + lane];
      float f1 = Ftab[(b+1)*KDIM + lane];
      float rw = f0 + fr*(f1 - f0);
      int snd = ei[e];
      acc += rw * hsrc[snd*KDIM + lane];
    }
  }
  acc *= (1.0f/AVG_NEI_F);
  lds[w][lane] = acc;
  __syncthreads();
  float a0 = 0.f;
  for (int k = 0; k < KDIM; k++) a0 += lds[w][k] * Wout_l0[k*KDIM + lane];
  A0_out[node*KDIM + lane] = a0;
  float t0 = theta_l[(0*ZDIM + z)*KDIM + lane];
  float t1 = theta_l[(1*ZDIM + z)*KDIM + lane];
  float t2 = theta_l[(2*ZDIM + z)*KDIM + lane];
  float q = t0 + t1*a0 + t2*a0*a0;
  __syncthreads();
  lds[w][lane] = q*a0;
  __syncthreads();
  float outv = 0.f;
  for (int k = 0; k < KDIM; k++) outv += lds[w][k] * Wmix_l[k*KDIM + lane];
  outv += (layer == 0) ? Msc0[z*KDIM + lane] : sc1[node*KDIM + lane];
  feats_out[node*KDIM + lane] = outv;
  if (layer == 0){
    float p = outv * w_read0[lane];
    p = waveReduce(p);
    if (lane == 0) e_node[node] += p;
  } else {
    __syncthreads();
    lds[w][lane] = outv;
    __syncthreads();
    int hh = lane & 15;
    int quad = lane >> 4;
    float tpart = 0.f;
    for (int jj = quad*16; jj < quad*16+16; jj++)
      tpart += lds[w][jj] * Wr1[jj*HIDR + hh];
    tpart += __shfl_xor(tpart, 16);
    tpart += __shfl_xor(tpart, 32);
    if (lane < 16) t_hid[node*HIDR + hh] = tpart;
    float ne = siluf(tpart) * Wr2[hh];
    ne = waveReduce(ne);   // every hh appears 4x across the wave
    if (lane == 0) e_node[node] += 0.25f * ne;
  }
}

__global__ __launch_bounds__(256) void k_h1sc1(const int* z_buf, const float* feats1,
                                               const float* Wup1, const float* Wsc1,
                                               float* h1, float* sc1){
  __shared__ float lds[4][KDIM];
  int tid = threadIdx.x; int w = tid>>6, lane = tid&63;
  int node = blockIdx.x*4 + w;
  lds[w][lane] = feats1[node*KDIM + lane];
  __syncthreads();
  int z = z_buf[node];
  float h = 0.f, s = 0.f;
  for (int k = 0; k < KDIM; k++){
    float f = lds[w][k];
    h += f * Wup1[k*KDIM + lane];
    s += f * Wsc1[(z*KDIM + k)*KDIM + lane];
  }
  h1[node*KDIM + lane] = h;
  sc1[node*KDIM + lane] = s;
}

__global__ __launch_bounds__(256) void k_energy(const float* e_node, const int* batch, float* out_e){
  __shared__ float part[G_SEG];
  int tid = threadIdx.x;
  if (tid < G_SEG) part[tid] = 0.f;
  __syncthreads();
  int n = blockIdx.x*256 + tid;
  if (n < N_NODES) atomicAdd(&part[batch[n]], e_node[n]);
  __syncthreads();
  if (tid < G_SEG) atomicAdd(&out_e[tid], part[tid]);
}

__global__ __launch_bounds__(256) void k_g2(const float* t_hid, const float* Wr1,
                                            const float* Wr2, float* gF2){
  int idx = blockIdx.x*256 + threadIdx.x;
  int n = idx >> 6, j = idx & 63;
  float g = 0.f;
  for (int hh = 0; hh < HIDR; hh++){
    float t = t_hid[n*HIDR + hh];
    g += dsiluf(t) * Wr2[hh] * Wr1[j*HIDR + hh];
  }
  gF2[idx] = g;
}

__global__ __launch_bounds__(256) void k_bwd_node(int layer,
    const int* z_buf, const float* gOut, const float* A0_l,
    const float* WmixT_l, const float* WoT_l, const float* theta_l,
    const float* WscT1, const float* w_read0,
    float* gAr_out, float* gF1){
  __shared__ float ga[4][KDIM];
  __shared__ float gb[4][KDIM];
  int tid = threadIdx.x; int w = tid>>6, lane = tid&63;
  int node = blockIdx.x*4 + w;
  ga[w][lane] = gOut[node*KDIM + lane];
  __syncthreads();
  float gP = 0.f;
  for (int j = 0; j < KDIM; j++) gP += ga[w][j] * WmixT_l[j*KDIM + lane];
  int z = z_buf[node];
  float a = A0_l[node*KDIM + lane];
  float t0 = theta_l[(0*ZDIM+z)*KDIM + lane];
  float t1 = theta_l[(1*ZDIM+z)*KDIM + lane];
  float t2 = theta_l[(2*ZDIM+z)*KDIM + lane];
  float u = t0 + 2.f*t1*a + 3.f*t2*a*a;
  gb[w][lane] = gP * u;
  __syncthreads();
  float gAr = 0.f;
  for (int j = 0; j < KDIM; j++) gAr += gb[w][j] * WoT_l[j*KDIM + lane];
  gAr_out[node*KDIM + lane] = gAr * (1.0f/AVG_NEI_F);
  if (layer == 1){
    float gsc = 0.f;
    for (int j = 0; j < KDIM; j++) gsc += ga[w][j] * WscT1[(z*KDIM + j)*KDIM + lane];
    gF1[node*KDIM + lane] = w_read0[lane] + gsc;
  }
}

__global__ __launch_bounds__(256) void k_bwd_gH(const int* ptr_s, const int* eid_s, const int* ei,
                                                const float* r_buf, const float* Ftab1,
                                                const float* gAr1, const float* WupT1, float* gF1){
  __shared__ float lds[4][KDIM];
  int tid = threadIdx.x; int w = tid>>6, lane = tid&63;
  int node = blockIdx.x*4 + w;
  float acc = 0.f;
  int beg = ptr_s[node], end = ptr_s[node+1];
  for (int idx = beg; idx < end; idx++){
    int e = eid_s[idx];
    float r = r_buf[e];
    if (r < RMAXF){
      float tp = r * (TBINS/RMAXF);
      int b = (int)tp; if (b > TBINS-1) b = TBINS-1;
      float fr = tp - (float)b;
      float f0 = Ftab1[b*KDIM+lane], f1 = Ftab1[(b+1)*KDIM+lane];
      float rw = f0 + fr*(f1-f0);
      int rcv = ei[N_EDGES + e];
      acc += gAr1[rcv*KDIM + lane] * rw;
    }
  }
  lds[w][lane] = acc;
  __syncthreads();
  float gfh = 0.f;
  for (int j = 0; j < KDIM; j++) gfh += lds[w][j] * WupT1[j*KDIM + lane];
  gF1[node*KDIM + lane] += gfh;
}

__global__ __launch_bounds__(256) void k_bwd_gr(int layer, const int* ei, const float* r_buf,
                                                const float* dFtab, const float* gAr,
                                                const float* hsrc, float* gr){
  int tid = threadIdx.x;
  int w = tid>>6, lane = tid&63;
  int e = blockIdx.x*4 + w;
  float r = r_buf[e];
  float v = 0.f;
  if (r < RMAXF){
    float tp = r * (TBINS/RMAXF);
    int b = (int)tp; if (b > TBINS-1) b = TBINS-1;
    float fr = tp - (float)b;
    float d0 = dFtab[b*KDIM+lane], d1 = dFtab[(b+1)*KDIM+lane];
    float dF = d0 + fr*(d1-d0);
    int snd = ei[e], rcv = ei[N_EDGES+e];
    v = gAr[rcv*KDIM+lane] * hsrc[snd*KDIM+lane] * dF;
  }
  v = waveReduce(v);
  if (lane == 0){
    if (layer == 1) gr[e] = v;
    else gr[e] += v;
  }
}

__global__ __launch_bounds__(256) void k_force(const int* ptr_r, const int* eid_r,
                                               const int* ptr_s, const int* eid_s,
                                               const float* gr, const float* r_buf,
                                               const float* vx, const float* vy, const float* vz,
                                               float* out_f){
  int tid = threadIdx.x; int w = tid>>6, lane = tid&63;
  int node = blockIdx.x*4 + w;
  float fx=0.f, fy=0.f, fz=0.f;
  int beg = ptr_r[node], end = ptr_r[node+1];
  for (int idx = beg + lane; idx < end; idx += 64){
    int e = eid_r[idx];
    float s = gr[e] / r_buf[e];
    fx -= s*vx[e]; fy -= s*vy[e]; fz -= s*vz[e];
  }
  beg = ptr_s[node]; end = ptr_s[node+1];
  for (int idx = beg + lane; idx < end; idx += 64){
    int e = eid_s[idx];
    float s = gr[e] / r_buf[e];
    fx += s*vx[e]; fy += s*vy[e]; fz += s*vz[e];
  }
  fx = waveReduce(fx); fy = waveReduce(fy); fz = waveReduce(fz);
  if (lane == 0){
    out_f[node*3+0] = fx; out_f[node*3+1] = fy; out_f[node*3+2] = fz;
  }
}

extern "C" void kernel_launch(void* const* d_in, const int* in_sizes, int n_in,
                              void* d_out, int out_size, void* d_ws, size_t ws_size,
                              hipStream_t stream){
  const float* pos    = (const float*)d_in[0];
  const float* attrs  = (const float*)d_in[1];
  const float* shifts = (const float*)d_in[2];
  const float* aE     = (const float*)d_in[3];
  const float* We     = (const float*)d_in[4];
  const float* Wup    = (const float*)d_in[5];
  const float* R1     = (const float*)d_in[6];
  const float* R2     = (const float*)d_in[7];
  const float* R3     = (const float*)d_in[8];
  const float* R4     = (const float*)d_in[9];
  const float* Wout   = (const float*)d_in[10];
  const float* Wsc    = (const float*)d_in[11];
  const float* theta  = (const float*)d_in[12];
  const float* Wmix   = (const float*)d_in[13];
  const float* w_read0= (const float*)d_in[14];
  const float* Wr1    = (const float*)d_in[15];
  const float* Wr2    = (const float*)d_in[16];
  const int*   ei     = (const int*)d_in[17];
  const int*   batch  = (const int*)d_in[18];

  char* base = (char*)d_ws;
  size_t off = 0;
  auto alloc = [&](size_t bytes)->void*{
    void* p = base + off;
    off = (off + bytes + 255) & ~(size_t)255;
    return p;
  };
  float* r_buf  = (float*)alloc(N_EDGES*sizeof(float));
  float* vx     = (float*)alloc(N_EDGES*sizeof(float));
  float* vy     = (float*)alloc(N_EDGES*sizeof(float));
  float* vz     = (float*)alloc(N_EDGES*sizeof(float));
  float* gr     = (float*)alloc(N_EDGES*sizeof(float));
  float* e_node = (float*)alloc(N_NODES*sizeof(float));
  float* h0     = (float*)alloc(N_NODES*KDIM*sizeof(float));
  float* feats1 = (float*)alloc(N_NODES*KDIM*sizeof(float));
  float* feats2 = (float*)alloc(N_NODES*KDIM*sizeof(float));
  float* h1     = (float*)alloc(N_NODES*KDIM*sizeof(float));
  float* sc1    = (float*)alloc(N_NODES*KDIM*sizeof(float));
  float* A00    = (float*)alloc(N_NODES*KDIM*sizeof(float));
  float* A01    = (float*)alloc(N_NODES*KDIM*sizeof(float));
  float* t_hid  = (float*)alloc(N_NODES*HIDR*sizeof(float));
  float* gF2    = (float*)alloc(N_NODES*KDIM*sizeof(float));
  float* gF1    = (float*)alloc(N_NODES*KDIM*sizeof(float));
  float* gAr1   = (float*)alloc(N_NODES*KDIM*sizeof(float));
  float* gAr0   = (float*)alloc(N_NODES*KDIM*sizeof(float));
  float* Ftab0  = (float*)alloc((TBINS+1)*KDIM*sizeof(float));
  float* Ftab1  = (float*)alloc((TBINS+1)*KDIM*sizeof(float));
  float* dF0    = (float*)alloc((TBINS+1)*KDIM*sizeof(float));
  float* dF1    = (float*)alloc((TBINS+1)*KDIM*sizeof(float));
  float* M0     = (float*)alloc(ZDIM*KDIM*sizeof(float));
  float* Msc0   = (float*)alloc(ZDIM*KDIM*sizeof(float));
  float* WoT0   = (float*)alloc(KDIM*KDIM*sizeof(float));
  float* WoT1   = (float*)alloc(KDIM*KDIM*sizeof(float));
  float* WmixT0 = (float*)alloc(KDIM*KDIM*sizeof(float));
  float* WmixT1 = (float*)alloc(KDIM*KDIM*sizeof(float));
  float* WupT1  = (float*)alloc(KDIM*KDIM*sizeof(float));
  float* WscT1  = (float*)alloc(ZDIM*KDIM*KDIM*sizeof(float));
  int* z_buf = (int*)alloc(N_NODES*sizeof(int));
  int* cnt_r = (int*)alloc(N_NODES*sizeof(int));
  int* cnt_s = (int*)alloc(N_NODES*sizeof(int));
  int* ptr_r = (int*)alloc((N_NODES+1)*sizeof(int));
  int* ptr_s = (int*)alloc((N_NODES+1)*sizeof(int));
  int* cur_r = (int*)alloc(N_NODES*sizeof(int));
  int* cur_s = (int*)alloc(N_NODES*sizeof(int));
  int* eid_r = (int*)alloc(N_EDGES*sizeof(int));
  int* eid_s = (int*)alloc(N_EDGES*sizeof(int));

  float* out_e = (float*)d_out;
  float* out_f = out_e + G_SEG;

  hipMemsetAsync(d_out, 0, (size_t)out_size*sizeof(float), stream);
  hipMemsetAsync(cnt_r, 0, N_NODES*sizeof(int), stream);
  hipMemsetAsync(cnt_s, 0, N_NODES*sizeof(int), stream);

  const int NB4 = N_NODES/4;       // 2500 blocks (wave per node)
  const int EB  = N_EDGES/256;     // 625
  const int EB4 = N_EDGES/4;       // 40000 (wave per edge)
  const int NBt = (N_NODES+255)/256; // 40

  k_prep<<<1,256,0,stream>>>(We, Wup, Wsc, Wout, Wmix, M0, Msc0,
                             WoT0, WoT1, WmixT0, WmixT1, WupT1, WscT1);
  k_node_init<<<NBt,256,0,stream>>>(attrs, aE, z_buf, e_node);
  k_h0<<<NB4,256,0,stream>>>(z_buf, M0, h0);
  k_edge_setup<<<EB,256,0,stream>>>(pos, shifts, ei, r_buf, vx, vy, vz);
  k_count<<<EB,256,0,stream>>>(ei, cnt_r, cnt_s);
  k_scan<<<1,1024,0,stream>>>(cnt_r, ptr_r, cur_r, cnt_s, ptr_s, cur_s);
  k_fill<<<EB,256,0,stream>>>(ei, cur_r, cur_s, eid_r, eid_s);
  k_table<<<TBINS+1,64,0,stream>>>(R1, R2, R3, R4, Ftab0, Ftab1, dF0, dF1);

  // ---- forward ----
  k_layer_fwd<<<NB4,256,0,stream>>>(0, z_buf, ptr_r, eid_r, ei, r_buf, Ftab0, h0,
      Wout, theta, Wmix, Msc0, sc1, w_read0, Wr1, Wr2,
      A00, feats1, t_hid, e_node);
  k_h1sc1<<<NB4,256,0,stream>>>(z_buf, feats1, Wup + KDIM*KDIM, Wsc + ZDIM*KDIM*KDIM, h1, sc1);
  k_layer_fwd<<<NB4,256,0,stream>>>(1, z_buf, ptr_r, eid_r, ei, r_buf, Ftab1, h1,
      Wout + 3*KDIM*KDIM, theta + 3*ZDIM*KDIM, Wmix + KDIM*KDIM, Msc0, sc1, w_read0, Wr1, Wr2,
      A01, feats2, t_hid, e_node);
  k_energy<<<NBt,256,0,stream>>>(e_node, batch, out_e);

  // ---- backward ----
  k_g2<<<NB4,256,0,stream>>>(t_hid, Wr1, Wr2, gF2);
  k_bwd_node<<<NB4,256,0,stream>>>(1, z_buf, gF2, A01, WmixT1, WoT1,
      theta + 3*ZDIM*KDIM, WscT1, w_read0, gAr1, gF1);
  k_bwd_gH<<<NB4,256,0,stream>>>(ptr_s, eid_s, ei, r_buf, Ftab1, gAr1, WupT1, gF1);
  k_bwd_gr<<<EB4,256,0,stream>>>(1, ei, r_buf, dF1, gAr1, h1, gr);
  k_bwd_node<<<NB4,256,0,stream>>>(0, z_buf, gF1, A00, WmixT0, WoT0,
      theta, WscT1, w_read0, gAr0, gF1);
  k_bwd_gr<<<EB4,256,0,stream>>>(0, ei, r_buf, dF0, gAr0, h0, gr);
  k_force<<<NB4,256,0,stream>>>(ptr_r, eid_r, ptr_s, eid_s, gr, r_buf, vx, vy, vz, out_f);
}

// Round 2
// 458.935 us; speedup vs baseline: 1.1983x; 1.1983x over previous
//
#include <hip/hip_runtime.h>
#include <math.h>

#define N_NODES 10000
#define N_EDGES 160000
#define G_SEG 16
#define ZDIM 10
#define KDIM 64
#define NBESS 8
#define HIDR 16
#define RMAXF 5.0f
#define AVG_NEI_F 16.0f
#define TBINS 1024

__device__ __forceinline__ float siluf(float x){ float s = 1.0f/(1.0f+expf(-x)); return x*s; }
__device__ __forceinline__ float dsiluf(float x){ float s = 1.0f/(1.0f+expf(-x)); return s*(1.0f + x*(1.0f-s)); }

__device__ __forceinline__ float waveReduce(float v){
  for (int off = 32; off > 0; off >>= 1) v += __shfl_down(v, off);
  return v;
}

// ---------------- parallel precompute: folded layer-0 node tensors ----------------
// 1280 threads: idx<640 -> M0[z][j], else Msc0[z][j]. Each is a dot over k=0..63.
__global__ __launch_bounds__(256) void k_prep_dots(
    const float* We, const float* Wup, const float* Wsc,
    float* M0, float* Msc0){
  int idx = blockIdx.x*256 + threadIdx.x;
  if (idx >= 1280) return;
  int which = idx >= 640;
  int t = which ? idx - 640 : idx;
  int z = t >> 6, j = t & 63;
  float acc = 0.f;
  if (!which){
    #pragma unroll 8
    for (int k = 0; k < KDIM; k++) acc += We[z*KDIM + k] * Wup[k*KDIM + j];
    M0[z*KDIM + j] = acc;
  } else {
    #pragma unroll 8
    for (int k = 0; k < KDIM; k++) acc += We[z*KDIM + k] * Wsc[(z*KDIM + k)*KDIM + j];
    Msc0[z*KDIM + j] = acc;
  }
}

// transposes: 5*4096 + 40960 = 61440 element copies, one per thread
__global__ __launch_bounds__(256) void k_prep_tr(
    const float* Wup, const float* Wsc, const float* Wout, const float* Wmix,
    float* WoT0, float* WoT1, float* WmixT0, float* WmixT1,
    float* WupT1, float* WscT1){
  int t = blockIdx.x*256 + threadIdx.x;
  if (t < 20480){
    int arr = t >> 12;         // 0..4
    int rem = t & 4095;
    int j = rem >> 6, k = rem & 63;
    float v;
    float* dst;
    switch(arr){
      case 0: v = Wout[k*KDIM + j];                 dst = WoT0;   break;
      case 1: v = Wout[3*KDIM*KDIM + k*KDIM + j];   dst = WoT1;   break;
      case 2: v = Wmix[k*KDIM + j];                 dst = WmixT0; break;
      case 3: v = Wmix[KDIM*KDIM + k*KDIM + j];     dst = WmixT1; break;
      default:v = Wup[KDIM*KDIM + k*KDIM + j];      dst = WupT1;  break;
    }
    dst[rem] = v;
  } else {
    int idx2 = t - 20480;       // 0..40959
    int z = idx2 >> 12;
    int rem = idx2 & 4095;
    int j = rem >> 6, k = rem & 63;
    WscT1[(z*KDIM + j)*KDIM + k] = Wsc[((ZDIM + z)*KDIM + k)*KDIM + j]; // W_sc[1,z]^T
  }
}

__global__ __launch_bounds__(256) void k_node_init(const float* attrs, const float* aE,
                                                   int* z_buf, float* e_node){
  int n = blockIdx.x*256 + threadIdx.x;
  if (n >= N_NODES) return;
  int z = 0;
  for (int i = 1; i < ZDIM; i++) if (attrs[n*ZDIM+i] > 0.5f) z = i;
  z_buf[n] = z;
  e_node[n] = aE[z];
}

__global__ __launch_bounds__(256) void k_h0(const int* z_buf, const float* M0, float* h0){
  int idx = blockIdx.x*256 + threadIdx.x;
  int n = idx >> 6, j = idx & 63;
  h0[idx] = M0[z_buf[n]*KDIM + j];
}

// fused: edge geometry + CSR degree counting
__global__ __launch_bounds__(256) void k_edge_setup(const float* pos, const float* shifts, const int* ei,
                                                    float* r_buf, float* vx, float* vy, float* vz,
                                                    int* cnt_r, int* cnt_s){
  int e = blockIdx.x*256 + threadIdx.x;
  int s = ei[e], rcv = ei[N_EDGES + e];
  float dx = pos[rcv*3+0] - pos[s*3+0] + shifts[e*3+0];
  float dy = pos[rcv*3+1] - pos[s*3+1] + shifts[e*3+1];
  float dz = pos[rcv*3+2] - pos[s*3+2] + shifts[e*3+2];
  float r = sqrtf(dx*dx + dy*dy + dz*dz + 1e-9f);
  r_buf[e] = r; vx[e] = dx; vy[e] = dy; vz[e] = dz;
  atomicAdd(&cnt_s[s], 1);
  atomicAdd(&cnt_r[rcv], 1);
}

__global__ __launch_bounds__(1024) void k_scan(const int* cnt_r, int* ptr_r, int* cur_r,
                                               const int* cnt_s, int* ptr_s, int* cur_s){
  __shared__ int part[1024];
  int tid = threadIdx.x;
  for (int pass = 0; pass < 2; pass++){
    const int* cnt = pass ? cnt_s : cnt_r;
    int* ptr = pass ? ptr_s : ptr_r;
    int* cur = pass ? cur_s : cur_r;
    const int per = 10; // 10*1024 >= N
    int start = tid*per;
    int s = 0;
    for (int t = 0; t < per; t++){ int i = start + t; if (i < N_NODES) s += cnt[i]; }
    part[tid] = s; __syncthreads();
    for (int d = 1; d < 1024; d <<= 1){
      int v = (tid >= d) ? part[tid-d] : 0;
      __syncthreads();
      part[tid] += v;
      __syncthreads();
    }
    int run = part[tid] - s; // exclusive prefix
    for (int t = 0; t < per; t++){
      int i = start + t;
      if (i < N_NODES){ ptr[i] = run; cur[i] = run; run += cnt[i]; }
    }
    if (tid == 1023) ptr[N_NODES] = part[1023];
    __syncthreads();
  }
}

__global__ __launch_bounds__(256) void k_fill(const int* ei, int* cur_r, int* cur_s,
                                              int* eid_r, int* eid_s){
  int e = blockIdx.x*256 + threadIdx.x;
  int p = atomicAdd(&cur_s[ei[e]], 1); eid_s[p] = e;
  int p2 = atomicAdd(&cur_r[ei[N_EDGES + e]], 1); eid_r[p2] = e;
}

// ---------------- radial-MLP table: F_i(r) and F_i'(r), both layers ----------------
__global__ __launch_bounds__(64) void k_table(const float* R1g, const float* R2g,
                                              const float* R3g, const float* R4g,
                                              float* Ftab0, float* Ftab1, float* dF0, float* dF1){
  int t = blockIdx.x, j = threadIdx.x;
  __shared__ float efs[NBESS], defs[NBESS];
  __shared__ float xs[KDIM], dxs[KDIM];
  if (j < NBESS){
    double r = (double)t * (double)RMAXF / (double)TBINS;
    double w = (double)(j+1) * M_PI / (double)RMAXF;
    double c = sqrt(2.0 / (double)RMAXF);
    double bess, dbess;
    if (r < 1e-12){ bess = c*w; dbess = 0.0; }
    else {
      double sw = sin(w*r), cw = cos(w*r);
      bess = c*sw/r;
      dbess = c*(w*cw*r - sw)/(r*r);
    }
    double xx = r / (double)RMAXF;
    double f = 0.0, df = 0.0;
    if (xx < 1.0){
      double x2 = xx*xx, x4 = x2*x2, x5 = x4*xx, x6 = x5*xx, x7 = x6*xx;
      f = 1.0 - 21.0*x5 + 35.0*x6 - 15.0*x7;
      df = (-105.0*x4 + 210.0*x5 - 105.0*x6) / (double)RMAXF;
    }
    efs[j]  = (float)(bess*f);
    defs[j] = (float)(dbess*f + bess*df);
  }
  __syncthreads();
  for (int i = 0; i < 2; i++){
    const float* R1 = R1g + i*NBESS*KDIM;
    const float* R2 = R2g + i*KDIM*KDIM;
    const float* R3 = R3g + i*KDIM*KDIM;
    const float* R4 = R4g + i*KDIM*KDIM;
    float z = 0.f, dz = 0.f;
    for (int b = 0; b < NBESS; b++){ float w = R1[b*KDIM+j]; z += efs[b]*w; dz += defs[b]*w; }
    float v = siluf(z), dv = dsiluf(z)*dz;
    xs[j] = v; dxs[j] = dv; __syncthreads();
    z = 0.f; dz = 0.f;
    for (int k = 0; k < KDIM; k++){ float w = R2[k*KDIM+j]; z += xs[k]*w; dz += dxs[k]*w; }
    v = siluf(z); dv = dsiluf(z)*dz; __syncthreads();
    xs[j] = v; dxs[j] = dv; __syncthreads();
    z = 0.f; dz = 0.f;
    for (int k = 0; k < KDIM; k++){ float w = R3[k*KDIM+j]; z += xs[k]*w; dz += dxs[k]*w; }
    v = siluf(z); dv = dsiluf(z)*dz; __syncthreads();
    xs[j] = v; dxs[j] = dv; __syncthreads();
    z = 0.f; dz = 0.f;
    for (int k = 0; k < KDIM; k++){ float w = R4[k*KDIM+j]; z += xs[k]*w; dz += dxs[k]*w; }
    float* Ft  = i ? Ftab1 : Ftab0;
    float* dFt = i ? dF1 : dF0;
    Ft[t*KDIM+j] = z; dFt[t*KDIM+j] = dz;
    __syncthreads();
  }
}

// ---------------- fused per-node forward layer (wave per node, lane = k) ----------------
__global__ __launch_bounds__(256) void k_layer_fwd(int layer,
    const int* z_buf, const int* ptr_r, const int* eid_r, const int* ei,
    const float* r_buf, const float* Ftab, const float* hsrc,
    const float* Wout_l0, const float* theta_l, const float* Wmix_l,
    const float* Msc0, const float* sc1,
    const float* w_read0, const float* Wr1, const float* Wr2,
    float* A0_out, float* feats_out, float* t_hid, float* e_node){
  __shared__ float lds[4][KDIM];
  int tid = threadIdx.x;
  int w = tid >> 6, lane = tid & 63;
  int node = blockIdx.x*4 + w;
  int z = z_buf[node];
  float acc = 0.f;
  int beg = ptr_r[node], end = ptr_r[node+1];
  for (int idx = beg; idx < end; idx++){
    int e = eid_r[idx];
    float r = r_buf[e];
    if (r < RMAXF){
      float tp = r * (TBINS / RMAXF);
      int b = (int)tp; if (b > TBINS-1) b = TBINS-1;
      float fr = tp - (float)b;
      float f0 = Ftab[b*KDIM + lane];
      float f1 = Ftab[(b+1)*KDIM + lane];
      float rw = f0 + fr*(f1 - f0);
      int snd = ei[e];
      acc += rw * hsrc[snd*KDIM + lane];
    }
  }
  acc *= (1.0f/AVG_NEI_F);
  lds[w][lane] = acc;
  __syncthreads();
  float a0 = 0.f;
  for (int k = 0; k < KDIM; k++) a0 += lds[w][k] * Wout_l0[k*KDIM + lane];
  A0_out[node*KDIM + lane] = a0;
  float t0 = theta_l[(0*ZDIM + z)*KDIM + lane];
  float t1 = theta_l[(1*ZDIM + z)*KDIM + lane];
  float t2 = theta_l[(2*ZDIM + z)*KDIM + lane];
  float q = t0 + t1*a0 + t2*a0*a0;
  __syncthreads();
  lds[w][lane] = q*a0;
  __syncthreads();
  float outv = 0.f;
  for (int k = 0; k < KDIM; k++) outv += lds[w][k] * Wmix_l[k*KDIM + lane];
  outv += (layer == 0) ? Msc0[z*KDIM + lane] : sc1[node*KDIM + lane];
  feats_out[node*KDIM + lane] = outv;
  if (layer == 0){
    float p = outv * w_read0[lane];
    p = waveReduce(p);
    if (lane == 0) e_node[node] += p;
  } else {
    __syncthreads();
    lds[w][lane] = outv;
    __syncthreads();
    int hh = lane & 15;
    int quad = lane >> 4;
    float tpart = 0.f;
    for (int jj = quad*16; jj < quad*16+16; jj++)
      tpart += lds[w][jj] * Wr1[jj*HIDR + hh];
    tpart += __shfl_xor(tpart, 16);
    tpart += __shfl_xor(tpart, 32);
    if (lane < 16) t_hid[node*HIDR + hh] = tpart;
    float ne = siluf(tpart) * Wr2[hh];
    ne = waveReduce(ne);   // every hh appears 4x across the wave
    if (lane == 0) e_node[node] += 0.25f * ne;
  }
}

__global__ __launch_bounds__(256) void k_h1sc1(const int* z_buf, const float* feats1,
                                               const float* Wup1, const float* Wsc1,
                                               float* h1, float* sc1){
  __shared__ float lds[4][KDIM];
  int tid = threadIdx.x; int w = tid>>6, lane = tid&63;
  int node = blockIdx.x*4 + w;
  lds[w][lane] = feats1[node*KDIM + lane];
  __syncthreads();
  int z = z_buf[node];
  float h = 0.f, s = 0.f;
  for (int k = 0; k < KDIM; k++){
    float f = lds[w][k];
    h += f * Wup1[k*KDIM + lane];
    s += f * Wsc1[(z*KDIM + k)*KDIM + lane];
  }
  h1[node*KDIM + lane] = h;
  sc1[node*KDIM + lane] = s;
}

__global__ __launch_bounds__(256) void k_energy(const float* e_node, const int* batch, float* out_e){
  __shared__ float part[G_SEG];
  int tid = threadIdx.x;
  if (tid < G_SEG) part[tid] = 0.f;
  __syncthreads();
  int n = blockIdx.x*256 + tid;
  if (n < N_NODES) atomicAdd(&part[batch[n]], e_node[n]);
  __syncthreads();
  if (tid < G_SEG) atomicAdd(&out_e[tid], part[tid]);
}

__global__ __launch_bounds__(256) void k_g2(const float* t_hid, const float* Wr1,
                                            const float* Wr2, float* gF2){
  int idx = blockIdx.x*256 + threadIdx.x;
  int n = idx >> 6, j = idx & 63;
  float g = 0.f;
  for (int hh = 0; hh < HIDR; hh++){
    float t = t_hid[n*HIDR + hh];
    g += dsiluf(t) * Wr2[hh] * Wr1[j*HIDR + hh];
  }
  gF2[idx] = g;
}

__global__ __launch_bounds__(256) void k_bwd_node(int layer,
    const int* z_buf, const float* gOut, const float* A0_l,
    const float* WmixT_l, const float* WoT_l, const float* theta_l,
    const float* WscT1, const float* w_read0,
    float* gAr_out, float* gF1){
  __shared__ float ga[4][KDIM];
  __shared__ float gb[4][KDIM];
  int tid = threadIdx.x; int w = tid>>6, lane = tid&63;
  int node = blockIdx.x*4 + w;
  ga[w][lane] = gOut[node*KDIM + lane];
  __syncthreads();
  float gP = 0.f;
  for (int j = 0; j < KDIM; j++) gP += ga[w][j] * WmixT_l[j*KDIM + lane];
  int z = z_buf[node];
  float a = A0_l[node*KDIM + lane];
  float t0 = theta_l[(0*ZDIM+z)*KDIM + lane];
  float t1 = theta_l[(1*ZDIM+z)*KDIM + lane];
  float t2 = theta_l[(2*ZDIM+z)*KDIM + lane];
  float u = t0 + 2.f*t1*a + 3.f*t2*a*a;
  gb[w][lane] = gP * u;
  __syncthreads();
  float gAr = 0.f;
  for (int j = 0; j < KDIM; j++) gAr += gb[w][j] * WoT_l[j*KDIM + lane];
  gAr_out[node*KDIM + lane] = gAr * (1.0f/AVG_NEI_F);
  if (layer == 1){
    float gsc = 0.f;
    for (int j = 0; j < KDIM; j++) gsc += ga[w][j] * WscT1[(z*KDIM + j)*KDIM + lane];
    gF1[node*KDIM + lane] = w_read0[lane] + gsc;
  }
}

__global__ __launch_bounds__(256) void k_bwd_gH(const int* ptr_s, const int* eid_s, const int* ei,
                                                const float* r_buf, const float* Ftab1,
                                                const float* gAr1, const float* WupT1, float* gF1){
  __shared__ float lds[4][KDIM];
  int tid = threadIdx.x; int w = tid>>6, lane = tid&63;
  int node = blockIdx.x*4 + w;
  float acc = 0.f;
  int beg = ptr_s[node], end = ptr_s[node+1];
  for (int idx = beg; idx < end; idx++){
    int e = eid_s[idx];
    float r = r_buf[e];
    if (r < RMAXF){
      float tp = r * (TBINS/RMAXF);
      int b = (int)tp; if (b > TBINS-1) b = TBINS-1;
      float fr = tp - (float)b;
      float f0 = Ftab1[b*KDIM+lane], f1 = Ftab1[(b+1)*KDIM+lane];
      float rw = f0 + fr*(f1-f0);
      int rcv = ei[N_EDGES + e];
      acc += gAr1[rcv*KDIM + lane] * rw;
    }
  }
  lds[w][lane] = acc;
  __syncthreads();
  float gfh = 0.f;
  for (int j = 0; j < KDIM; j++) gfh += lds[w][j] * WupT1[j*KDIM + lane];
  gF1[node*KDIM + lane] += gfh;
}

__global__ __launch_bounds__(256) void k_bwd_gr(int layer, const int* ei, const float* r_buf,
                                                const float* dFtab, const float* gAr,
                                                const float* hsrc, float* gr){
  int tid = threadIdx.x;
  int w = tid>>6, lane = tid&63;
  int e = blockIdx.x*4 + w;
  float r = r_buf[e];
  float v = 0.f;
  if (r < RMAXF){
    float tp = r * (TBINS/RMAXF);
    int b = (int)tp; if (b > TBINS-1) b = TBINS-1;
    float fr = tp - (float)b;
    float d0 = dFtab[b*KDIM+lane], d1 = dFtab[(b+1)*KDIM+lane];
    float dF = d0 + fr*(d1-d0);
    int snd = ei[e], rcv = ei[N_EDGES+e];
    v = gAr[rcv*KDIM+lane] * hsrc[snd*KDIM+lane] * dF;
  }
  v = waveReduce(v);
  if (lane == 0){
    if (layer == 1) gr[e] = v;
    else gr[e] += v;
  }
}

__global__ __launch_bounds__(256) void k_force(const int* ptr_r, const int* eid_r,
                                               const int* ptr_s, const int* eid_s,
                                               const float* gr, const float* r_buf,
                                               const float* vx, const float* vy, const float* vz,
                                               float* out_f){
  int tid = threadIdx.x; int w = tid>>6, lane = tid&63;
  int node = blockIdx.x*4 + w;
  float fx=0.f, fy=0.f, fz=0.f;
  int beg = ptr_r[node], end = ptr_r[node+1];
  for (int idx = beg + lane; idx < end; idx += 64){
    int e = eid_r[idx];
    float s = gr[e] / r_buf[e];
    fx -= s*vx[e]; fy -= s*vy[e]; fz -= s*vz[e];
  }
  beg = ptr_s[node]; end = ptr_s[node+1];
  for (int idx = beg + lane; idx < end; idx += 64){
    int e = eid_s[idx];
    float s = gr[e] / r_buf[e];
    fx += s*vx[e]; fy += s*vy[e]; fz += s*vz[e];
  }
  fx = waveReduce(fx); fy = waveReduce(fy); fz = waveReduce(fz);
  if (lane == 0){
    out_f[node*3+0] = fx; out_f[node*3+1] = fy; out_f[node*3+2] = fz;
  }
}

extern "C" void kernel_launch(void* const* d_in, const int* in_sizes, int n_in,
                              void* d_out, int out_size, void* d_ws, size_t ws_size,
                              hipStream_t stream){
  const float* pos    = (const float*)d_in[0];
  const float* attrs  = (const float*)d_in[1];
  const float* shifts = (const float*)d_in[2];
  const float* aE     = (const float*)d_in[3];
  const float* We     = (const float*)d_in[4];
  const float* Wup    = (const float*)d_in[5];
  const float* R1     = (const float*)d_in[6];
  const float* R2     = (const float*)d_in[7];
  const float* R3     = (const float*)d_in[8];
  const float* R4     = (const float*)d_in[9];
  const float* Wout   = (const float*)d_in[10];
  const float* Wsc    = (const float*)d_in[11];
  const float* theta  = (const float*)d_in[12];
  const float* Wmix   = (const float*)d_in[13];
  const float* w_read0= (const float*)d_in[14];
  const float* Wr1    = (const float*)d_in[15];
  const float* Wr2    = (const float*)d_in[16];
  const int*   ei     = (const int*)d_in[17];
  const int*   batch  = (const int*)d_in[18];

  char* base = (char*)d_ws;
  size_t off = 0;
  auto alloc = [&](size_t bytes)->void*{
    void* p = base + off;
    off = (off + bytes + 255) & ~(size_t)255;
    return p;
  };
  float* r_buf  = (float*)alloc(N_EDGES*sizeof(float));
  float* vx     = (float*)alloc(N_EDGES*sizeof(float));
  float* vy     = (float*)alloc(N_EDGES*sizeof(float));
  float* vz     = (float*)alloc(N_EDGES*sizeof(float));
  float* gr     = (float*)alloc(N_EDGES*sizeof(float));
  float* e_node = (float*)alloc(N_NODES*sizeof(float));
  float* h0     = (float*)alloc(N_NODES*KDIM*sizeof(float));
  float* feats1 = (float*)alloc(N_NODES*KDIM*sizeof(float));
  float* feats2 = (float*)alloc(N_NODES*KDIM*sizeof(float));
  float* h1     = (float*)alloc(N_NODES*KDIM*sizeof(float));
  float* sc1    = (float*)alloc(N_NODES*KDIM*sizeof(float));
  float* A00    = (float*)alloc(N_NODES*KDIM*sizeof(float));
  float* A01    = (float*)alloc(N_NODES*KDIM*sizeof(float));
  float* t_hid  = (float*)alloc(N_NODES*HIDR*sizeof(float));
  float* gF2    = (float*)alloc(N_NODES*KDIM*sizeof(float));
  float* gF1    = (float*)alloc(N_NODES*KDIM*sizeof(float));
  float* gAr1   = (float*)alloc(N_NODES*KDIM*sizeof(float));
  float* gAr0   = (float*)alloc(N_NODES*KDIM*sizeof(float));
  float* Ftab0  = (float*)alloc((TBINS+1)*KDIM*sizeof(float));
  float* Ftab1  = (float*)alloc((TBINS+1)*KDIM*sizeof(float));
  float* dF0    = (float*)alloc((TBINS+1)*KDIM*sizeof(float));
  float* dF1    = (float*)alloc((TBINS+1)*KDIM*sizeof(float));
  float* M0     = (float*)alloc(ZDIM*KDIM*sizeof(float));
  float* Msc0   = (float*)alloc(ZDIM*KDIM*sizeof(float));
  float* WoT0   = (float*)alloc(KDIM*KDIM*sizeof(float));
  float* WoT1   = (float*)alloc(KDIM*KDIM*sizeof(float));
  float* WmixT0 = (float*)alloc(KDIM*KDIM*sizeof(float));
  float* WmixT1 = (float*)alloc(KDIM*KDIM*sizeof(float));
  float* WupT1  = (float*)alloc(KDIM*KDIM*sizeof(float));
  float* WscT1  = (float*)alloc(ZDIM*KDIM*KDIM*sizeof(float));
  int* z_buf = (int*)alloc(N_NODES*sizeof(int));
  int* cnt_r = (int*)alloc(N_NODES*sizeof(int));
  int* cnt_s = (int*)alloc(N_NODES*sizeof(int));
  int* ptr_r = (int*)alloc((N_NODES+1)*sizeof(int));
  int* ptr_s = (int*)alloc((N_NODES+1)*sizeof(int));
  int* cur_r = (int*)alloc(N_NODES*sizeof(int));
  int* cur_s = (int*)alloc(N_NODES*sizeof(int));
  int* eid_r = (int*)alloc(N_EDGES*sizeof(int));
  int* eid_s = (int*)alloc(N_EDGES*sizeof(int));

  float* out_e = (float*)d_out;
  float* out_f = out_e + G_SEG;

  hipMemsetAsync(d_out, 0, (size_t)out_size*sizeof(float), stream);
  hipMemsetAsync(cnt_r, 0, N_NODES*sizeof(int), stream);
  hipMemsetAsync(cnt_s, 0, N_NODES*sizeof(int), stream);

  const int NB4 = N_NODES/4;       // 2500 blocks (wave per node)
  const int EB  = N_EDGES/256;     // 625
  const int EB4 = N_EDGES/4;       // 40000 (wave per edge)
  const int NBt = (N_NODES+255)/256; // 40

  k_prep_dots<<<5,256,0,stream>>>(We, Wup, Wsc, M0, Msc0);
  k_prep_tr<<<240,256,0,stream>>>(Wup, Wsc, Wout, Wmix,
                                  WoT0, WoT1, WmixT0, WmixT1, WupT1, WscT1);
  k_node_init<<<NBt,256,0,stream>>>(attrs, aE, z_buf, e_node);
  k_h0<<<NB4,256,0,stream>>>(z_buf, M0, h0);
  k_edge_setup<<<EB,256,0,stream>>>(pos, shifts, ei, r_buf, vx, vy, vz, cnt_r, cnt_s);
  k_scan<<<1,1024,0,stream>>>(cnt_r, ptr_r, cur_r, cnt_s, ptr_s, cur_s);
  k_fill<<<EB,256,0,stream>>>(ei, cur_r, cur_s, eid_r, eid_s);
  k_table<<<TBINS+1,64,0,stream>>>(R1, R2, R3, R4, Ftab0, Ftab1, dF0, dF1);

  // ---- forward ----
  k_layer_fwd<<<NB4,256,0,stream>>>(0, z_buf, ptr_r, eid_r, ei, r_buf, Ftab0, h0,
      Wout, theta, Wmix, Msc0, sc1, w_read0, Wr1, Wr2,
      A00, feats1, t_hid, e_node);
  k_h1sc1<<<NB4,256,0,stream>>>(z_buf, feats1, Wup + KDIM*KDIM, Wsc + ZDIM*KDIM*KDIM, h1, sc1);
  k_layer_fwd<<<NB4,256,0,stream>>>(1, z_buf, ptr_r, eid_r, ei, r_buf, Ftab1, h1,
      Wout + 3*KDIM*KDIM, theta + 3*ZDIM*KDIM, Wmix + KDIM*KDIM, Msc0, sc1, w_read0, Wr1, Wr2,
      A01, feats2, t_hid, e_node);
  k_energy<<<NBt,256,0,stream>>>(e_node, batch, out_e);

  // ---- backward ----
  k_g2<<<NB4,256,0,stream>>>(t_hid, Wr1, Wr2, gF2);
  k_bwd_node<<<NB4,256,0,stream>>>(1, z_buf, gF2, A01, WmixT1, WoT1,
      theta + 3*ZDIM*KDIM, WscT1, w_read0, gAr1, gF1);
  k_bwd_gH<<<NB4,256,0,stream>>>(ptr_s, eid_s, ei, r_buf, Ftab1, gAr1, WupT1, gF1);
  k_bwd_gr<<<EB4,256,0,stream>>>(1, ei, r_buf, dF1, gAr1, h1, gr);
  k_bwd_node<<<NB4,256,0,stream>>>(0, z_buf, gF1, A00, WmixT0, WoT0,
      theta, WscT1, w_read0, gAr0, gF1);
  k_bwd_gr<<<EB4,256,0,stream>>>(0, ei, r_buf, dF0, gAr0, h0, gr);
  k_force<<<NB4,256,0,stream>>>(ptr_r, eid_r, ptr_s, eid_s, gr, r_buf, vx, vy, vz, out_f);
}

// Round 3
// 343.769 us; speedup vs baseline: 1.5997x; 1.3350x over previous
//
#include <hip/hip_runtime.h>
#include <math.h>

#define N_NODES 10000
#define N_EDGES 160000
#define G_SEG 16
#define ZDIM 10
#define KDIM 64
#define NBESS 8
#define HIDR 16
#define RMAXF 5.0f
#define AVG_NEI_F 16.0f
#define TBINS 1024

__device__ __forceinline__ float siluf(float x){ float s = 1.0f/(1.0f+expf(-x)); return x*s; }
__device__ __forceinline__ float dsiluf(float x){ float s = 1.0f/(1.0f+expf(-x)); return s*(1.0f + x*(1.0f-s)); }

__device__ __forceinline__ float waveReduce(float v){
  for (int off = 32; off > 0; off >>= 1) v += __shfl_down(v, off);
  return v;
}

// decode tp -> (bin, frac, mask). tp<0 means r>=RMAX (contribution 0).
__device__ __forceinline__ void tp_decode(float tp, int& b, float& fr, float& wm){
  float tpe = fmaxf(tp, 0.f);
  b = (int)tpe; if (b > TBINS-1) b = TBINS-1;
  fr = tpe - (float)b;
  wm = (tp >= 0.f) ? 1.f : 0.f;
}

// ---------------- parallel precompute: folded layer-0 node tensors ----------------
__global__ __launch_bounds__(256) void k_prep_dots(
    const float* We, const float* Wup, const float* Wsc,
    float* M0, float* Msc0){
  int idx = blockIdx.x*256 + threadIdx.x;
  if (idx >= 1280) return;
  int which = idx >= 640;
  int t = which ? idx - 640 : idx;
  int z = t >> 6, j = t & 63;
  float acc = 0.f;
  if (!which){
    #pragma unroll 8
    for (int k = 0; k < KDIM; k++) acc += We[z*KDIM + k] * Wup[k*KDIM + j];
    M0[z*KDIM + j] = acc;
  } else {
    #pragma unroll 8
    for (int k = 0; k < KDIM; k++) acc += We[z*KDIM + k] * Wsc[(z*KDIM + k)*KDIM + j];
    Msc0[z*KDIM + j] = acc;
  }
}

__global__ __launch_bounds__(256) void k_prep_tr(
    const float* Wup, const float* Wsc, const float* Wout, const float* Wmix,
    float* WoT0, float* WoT1, float* WmixT0, float* WmixT1,
    float* WupT1, float* WscT1){
  int t = blockIdx.x*256 + threadIdx.x;
  if (t < 20480){
    int arr = t >> 12;
    int rem = t & 4095;
    int j = rem >> 6, k = rem & 63;
    float v;
    float* dst;
    switch(arr){
      case 0: v = Wout[k*KDIM + j];                 dst = WoT0;   break;
      case 1: v = Wout[3*KDIM*KDIM + k*KDIM + j];   dst = WoT1;   break;
      case 2: v = Wmix[k*KDIM + j];                 dst = WmixT0; break;
      case 3: v = Wmix[KDIM*KDIM + k*KDIM + j];     dst = WmixT1; break;
      default:v = Wup[KDIM*KDIM + k*KDIM + j];      dst = WupT1;  break;
    }
    dst[rem] = v;
  } else {
    int idx2 = t - 20480;
    int z = idx2 >> 12;
    int rem = idx2 & 4095;
    int j = rem >> 6, k = rem & 63;
    WscT1[(z*KDIM + j)*KDIM + k] = Wsc[((ZDIM + z)*KDIM + k)*KDIM + j];
  }
}

__global__ __launch_bounds__(256) void k_node_init(const float* attrs, const float* aE,
                                                   int* z_buf, float* e_node){
  int n = blockIdx.x*256 + threadIdx.x;
  if (n >= N_NODES) return;
  int z = 0;
  for (int i = 1; i < ZDIM; i++) if (attrs[n*ZDIM+i] > 0.5f) z = i;
  z_buf[n] = z;
  e_node[n] = aE[z];
}

__global__ __launch_bounds__(256) void k_h0(const int* z_buf, const float* M0, float* h0){
  int idx = blockIdx.x*256 + threadIdx.x;
  int n = idx >> 6, j = idx & 63;
  h0[idx] = M0[z_buf[n]*KDIM + j];
}

// fused: edge geometry + table position + CSR degree counting
__global__ __launch_bounds__(256) void k_edge_setup(const float* pos, const float* shifts, const int* ei,
                                                    float* r_buf, float* tp_buf,
                                                    float* vx, float* vy, float* vz,
                                                    int* cnt_r, int* cnt_s){
  int e = blockIdx.x*256 + threadIdx.x;
  int s = ei[e], rcv = ei[N_EDGES + e];
  float dx = pos[rcv*3+0] - pos[s*3+0] + shifts[e*3+0];
  float dy = pos[rcv*3+1] - pos[s*3+1] + shifts[e*3+1];
  float dz = pos[rcv*3+2] - pos[s*3+2] + shifts[e*3+2];
  float r = sqrtf(dx*dx + dy*dy + dz*dz + 1e-9f);
  r_buf[e] = r; vx[e] = dx; vy[e] = dy; vz[e] = dz;
  tp_buf[e] = (r < RMAXF) ? r * (TBINS / RMAXF) : -1.f;
  atomicAdd(&cnt_s[s], 1);
  atomicAdd(&cnt_r[rcv], 1);
}

__global__ __launch_bounds__(1024) void k_scan(const int* cnt_r, int* ptr_r, int* cur_r,
                                               const int* cnt_s, int* ptr_s, int* cur_s){
  __shared__ int part[1024];
  int tid = threadIdx.x;
  for (int pass = 0; pass < 2; pass++){
    const int* cnt = pass ? cnt_s : cnt_r;
    int* ptr = pass ? ptr_s : ptr_r;
    int* cur = pass ? cur_s : cur_r;
    const int per = 10;
    int start = tid*per;
    int s = 0;
    for (int t = 0; t < per; t++){ int i = start + t; if (i < N_NODES) s += cnt[i]; }
    part[tid] = s; __syncthreads();
    for (int d = 1; d < 1024; d <<= 1){
      int v = (tid >= d) ? part[tid-d] : 0;
      __syncthreads();
      part[tid] += v;
      __syncthreads();
    }
    int run = part[tid] - s;
    for (int t = 0; t < per; t++){
      int i = start + t;
      if (i < N_NODES){ ptr[i] = run; cur[i] = run; run += cnt[i]; }
    }
    if (tid == 1023) ptr[N_NODES] = part[1023];
    __syncthreads();
  }
}

__global__ __launch_bounds__(256) void k_fill(const int* ei, int* cur_r, int* cur_s,
                                              int* eid_r, int* eid_s){
  int e = blockIdx.x*256 + threadIdx.x;
  int p = atomicAdd(&cur_s[ei[e]], 1); eid_s[p] = e;
  int p2 = atomicAdd(&cur_r[ei[N_EDGES + e]], 1); eid_r[p2] = e;
}

// ---------------- radial-MLP tables, packed float2 (F[b], F[b+1]) ----------------
__global__ __launch_bounds__(64) void k_table(const float* R1g, const float* R2g,
                                              const float* R3g, const float* R4g,
                                              float2* Ft2_0, float2* Ft2_1,
                                              float2* dF2_0, float2* dF2_1){
  int t = blockIdx.x, j = threadIdx.x;
  __shared__ float efs[NBESS], defs[NBESS];
  __shared__ float xs[KDIM], dxs[KDIM];
  if (j < NBESS){
    double r = (double)t * (double)RMAXF / (double)TBINS;
    double w = (double)(j+1) * M_PI / (double)RMAXF;
    double c = sqrt(2.0 / (double)RMAXF);
    double bess, dbess;
    if (r < 1e-12){ bess = c*w; dbess = 0.0; }
    else {
      double sw = sin(w*r), cw = cos(w*r);
      bess = c*sw/r;
      dbess = c*(w*cw*r - sw)/(r*r);
    }
    double xx = r / (double)RMAXF;
    double f = 0.0, df = 0.0;
    if (xx < 1.0){
      double x2 = xx*xx, x4 = x2*x2, x5 = x4*xx, x6 = x5*xx, x7 = x6*xx;
      f = 1.0 - 21.0*x5 + 35.0*x6 - 15.0*x7;
      df = (-105.0*x4 + 210.0*x5 - 105.0*x6) / (double)RMAXF;
    }
    efs[j]  = (float)(bess*f);
    defs[j] = (float)(dbess*f + bess*df);
  }
  __syncthreads();
  for (int i = 0; i < 2; i++){
    const float* R1 = R1g + i*NBESS*KDIM;
    const float* R2 = R2g + i*KDIM*KDIM;
    const float* R3 = R3g + i*KDIM*KDIM;
    const float* R4 = R4g + i*KDIM*KDIM;
    float z = 0.f, dz = 0.f;
    for (int b = 0; b < NBESS; b++){ float w = R1[b*KDIM+j]; z += efs[b]*w; dz += defs[b]*w; }
    float v = siluf(z), dv = dsiluf(z)*dz;
    xs[j] = v; dxs[j] = dv; __syncthreads();
    z = 0.f; dz = 0.f;
    for (int k = 0; k < KDIM; k++){ float w = R2[k*KDIM+j]; z += xs[k]*w; dz += dxs[k]*w; }
    v = siluf(z); dv = dsiluf(z)*dz; __syncthreads();
    xs[j] = v; dxs[j] = dv; __syncthreads();
    z = 0.f; dz = 0.f;
    for (int k = 0; k < KDIM; k++){ float w = R3[k*KDIM+j]; z += xs[k]*w; dz += dxs[k]*w; }
    v = siluf(z); dv = dsiluf(z)*dz; __syncthreads();
    xs[j] = v; dxs[j] = dv; __syncthreads();
    z = 0.f; dz = 0.f;
    for (int k = 0; k < KDIM; k++){ float w = R4[k*KDIM+j]; z += xs[k]*w; dz += dxs[k]*w; }
    float2* Ft  = i ? Ft2_1 : Ft2_0;
    float2* dFt = i ? dF2_1 : dF2_0;
    Ft[t*KDIM+j].x = z;  if (t > 0) Ft[(t-1)*KDIM+j].y = z;
    dFt[t*KDIM+j].x = dz; if (t > 0) dFt[(t-1)*KDIM+j].y = dz;
    __syncthreads();
  }
}

// ---------------- fused per-node forward layer (wave per node, lane = k) ----------------
// gather: cooperative 64-edge meta load + shuffle broadcast, x4 unroll, float2 table.
__global__ __launch_bounds__(256) void k_layer_fwd(int layer,
    const int* z_buf, const int* ptr_r, const int* eid_r, const int* ei,
    const float* tp_buf, const float2* Ft2, const float* hsrc,
    const float* Wout_l0, const float* theta_l, const float* Wmix_l,
    const float* Msc0, const float* sc1,
    const float* w_read0, const float* Wr1, const float* Wr2,
    float* A0_out, float* feats_out, float* t_hid, float* e_node){
  __shared__ float lds[4][KDIM];
  int tid = threadIdx.x;
  int w = tid >> 6, lane = tid & 63;
  int node = blockIdx.x*4 + w;
  int z = z_buf[node];
  int beg = ptr_r[node], end = ptr_r[node+1];
  int deg = end - beg;
  float acc0 = 0.f, acc1 = 0.f, acc2 = 0.f, acc3 = 0.f;
  for (int base = 0; base < deg; base += 64){
    int m = min(64, deg - base);
    float tp_l = -1.f; int snd_l = 0;
    if (lane < m){
      int e = eid_r[beg + base + lane];
      tp_l = tp_buf[e];
      snd_l = ei[e];
    }
    int i = 0;
    for (; i + 4 <= m; i += 4){
      float tpa = __shfl(tp_l, i),   tpb = __shfl(tp_l, i+1);
      float tpc = __shfl(tp_l, i+2), tpd = __shfl(tp_l, i+3);
      int sa = __shfl(snd_l, i),   sb = __shfl(snd_l, i+1);
      int sc = __shfl(snd_l, i+2), sd = __shfl(snd_l, i+3);
      int ba, bb, bc, bd; float fa, fb, fc, fd, wa, wb, wc, wd;
      tp_decode(tpa, ba, fa, wa); tp_decode(tpb, bb, fb, wb);
      tp_decode(tpc, bc, fc, wc); tp_decode(tpd, bd, fd, wd);
      float2 Fa = Ft2[ba*KDIM + lane]; float ha = hsrc[sa*KDIM + lane];
      float2 Fb = Ft2[bb*KDIM + lane]; float hb = hsrc[sb*KDIM + lane];
      float2 Fc = Ft2[bc*KDIM + lane]; float hc = hsrc[sc*KDIM + lane];
      float2 Fd = Ft2[bd*KDIM + lane]; float hd = hsrc[sd*KDIM + lane];
      acc0 += wa * (Fa.x + fa*(Fa.y - Fa.x)) * ha;
      acc1 += wb * (Fb.x + fb*(Fb.y - Fb.x)) * hb;
      acc2 += wc * (Fc.x + fc*(Fc.y - Fc.x)) * hc;
      acc3 += wd * (Fd.x + fd*(Fd.y - Fd.x)) * hd;
    }
    for (; i < m; i++){
      float tpa = __shfl(tp_l, i);
      int sa = __shfl(snd_l, i);
      int ba; float fa, wa;
      tp_decode(tpa, ba, fa, wa);
      float2 Fa = Ft2[ba*KDIM + lane]; float ha = hsrc[sa*KDIM + lane];
      acc0 += wa * (Fa.x + fa*(Fa.y - Fa.x)) * ha;
    }
  }
  float acc = ((acc0 + acc1) + (acc2 + acc3)) * (1.0f/AVG_NEI_F);
  lds[w][lane] = acc;
  __syncthreads();
  float a0 = 0.f;
  for (int k = 0; k < KDIM; k++) a0 += lds[w][k] * Wout_l0[k*KDIM + lane];
  A0_out[node*KDIM + lane] = a0;
  float t0 = theta_l[(0*ZDIM + z)*KDIM + lane];
  float t1 = theta_l[(1*ZDIM + z)*KDIM + lane];
  float t2 = theta_l[(2*ZDIM + z)*KDIM + lane];
  float q = t0 + t1*a0 + t2*a0*a0;
  __syncthreads();
  lds[w][lane] = q*a0;
  __syncthreads();
  float outv = 0.f;
  for (int k = 0; k < KDIM; k++) outv += lds[w][k] * Wmix_l[k*KDIM + lane];
  outv += (layer == 0) ? Msc0[z*KDIM + lane] : sc1[node*KDIM + lane];
  feats_out[node*KDIM + lane] = outv;
  if (layer == 0){
    float p = outv * w_read0[lane];
    p = waveReduce(p);
    if (lane == 0) e_node[node] += p;
  } else {
    __syncthreads();
    lds[w][lane] = outv;
    __syncthreads();
    int hh = lane & 15;
    int quad = lane >> 4;
    float tpart = 0.f;
    for (int jj = quad*16; jj < quad*16+16; jj++)
      tpart += lds[w][jj] * Wr1[jj*HIDR + hh];
    tpart += __shfl_xor(tpart, 16);
    tpart += __shfl_xor(tpart, 32);
    if (lane < 16) t_hid[node*HIDR + hh] = tpart;
    float ne = siluf(tpart) * Wr2[hh];
    ne = waveReduce(ne);
    if (lane == 0) e_node[node] += 0.25f * ne;
  }
}

__global__ __launch_bounds__(256) void k_h1sc1(const int* z_buf, const float* feats1,
                                               const float* Wup1, const float* Wsc1,
                                               float* h1, float* sc1){
  __shared__ float lds[4][KDIM];
  int tid = threadIdx.x; int w = tid>>6, lane = tid&63;
  int node = blockIdx.x*4 + w;
  lds[w][lane] = feats1[node*KDIM + lane];
  __syncthreads();
  int z = z_buf[node];
  float h = 0.f, s = 0.f;
  for (int k = 0; k < KDIM; k++){
    float f = lds[w][k];
    h += f * Wup1[k*KDIM + lane];
    s += f * Wsc1[(z*KDIM + k)*KDIM + lane];
  }
  h1[node*KDIM + lane] = h;
  sc1[node*KDIM + lane] = s;
}

__global__ __launch_bounds__(256) void k_energy(const float* e_node, const int* batch, float* out_e){
  __shared__ float part[G_SEG];
  int tid = threadIdx.x;
  if (tid < G_SEG) part[tid] = 0.f;
  __syncthreads();
  int n = blockIdx.x*256 + tid;
  if (n < N_NODES) atomicAdd(&part[batch[n]], e_node[n]);
  __syncthreads();
  if (tid < G_SEG) atomicAdd(&out_e[tid], part[tid]);
}

__global__ __launch_bounds__(256) void k_g2(const float* t_hid, const float* Wr1,
                                            const float* Wr2, float* gF2){
  int idx = blockIdx.x*256 + threadIdx.x;
  int n = idx >> 6, j = idx & 63;
  float g = 0.f;
  for (int hh = 0; hh < HIDR; hh++){
    float t = t_hid[n*HIDR + hh];
    g += dsiluf(t) * Wr2[hh] * Wr1[j*HIDR + hh];
  }
  gF2[idx] = g;
}

__global__ __launch_bounds__(256) void k_bwd_node(int layer,
    const int* z_buf, const float* gOut, const float* A0_l,
    const float* WmixT_l, const float* WoT_l, const float* theta_l,
    const float* WscT1, const float* w_read0,
    float* gAr_out, float* gF1){
  __shared__ float ga[4][KDIM];
  __shared__ float gb[4][KDIM];
  int tid = threadIdx.x; int w = tid>>6, lane = tid&63;
  int node = blockIdx.x*4 + w;
  ga[w][lane] = gOut[node*KDIM + lane];
  __syncthreads();
  float gP = 0.f;
  for (int j = 0; j < KDIM; j++) gP += ga[w][j] * WmixT_l[j*KDIM + lane];
  int z = z_buf[node];
  float a = A0_l[node*KDIM + lane];
  float t0 = theta_l[(0*ZDIM+z)*KDIM + lane];
  float t1 = theta_l[(1*ZDIM+z)*KDIM + lane];
  float t2 = theta_l[(2*ZDIM+z)*KDIM + lane];
  float u = t0 + 2.f*t1*a + 3.f*t2*a*a;
  gb[w][lane] = gP * u;
  __syncthreads();
  float gAr = 0.f;
  for (int j = 0; j < KDIM; j++) gAr += gb[w][j] * WoT_l[j*KDIM + lane];
  gAr_out[node*KDIM + lane] = gAr * (1.0f/AVG_NEI_F);
  if (layer == 1){
    float gsc = 0.f;
    for (int j = 0; j < KDIM; j++) gsc += ga[w][j] * WscT1[(z*KDIM + j)*KDIM + lane];
    gF1[node*KDIM + lane] = w_read0[lane] + gsc;
  }
}

// gather by sender: gH[n] = sum_out rw1(e) * gAr1[rcv], then @ WupT1
__global__ __launch_bounds__(256) void k_bwd_gH(const int* ptr_s, const int* eid_s, const int* ei,
                                                const float* tp_buf, const float2* Ft2_1,
                                                const float* gAr1, const float* WupT1, float* gF1){
  __shared__ float lds[4][KDIM];
  int tid = threadIdx.x; int w = tid>>6, lane = tid&63;
  int node = blockIdx.x*4 + w;
  int beg = ptr_s[node], end = ptr_s[node+1];
  int deg = end - beg;
  float acc0 = 0.f, acc1 = 0.f, acc2 = 0.f, acc3 = 0.f;
  for (int base = 0; base < deg; base += 64){
    int m = min(64, deg - base);
    float tp_l = -1.f; int rcv_l = 0;
    if (lane < m){
      int e = eid_s[beg + base + lane];
      tp_l = tp_buf[e];
      rcv_l = ei[N_EDGES + e];
    }
    int i = 0;
    for (; i + 4 <= m; i += 4){
      float tpa = __shfl(tp_l, i),   tpb = __shfl(tp_l, i+1);
      float tpc = __shfl(tp_l, i+2), tpd = __shfl(tp_l, i+3);
      int ra = __shfl(rcv_l, i),   rb = __shfl(rcv_l, i+1);
      int rc = __shfl(rcv_l, i+2), rd = __shfl(rcv_l, i+3);
      int ba, bb, bc, bd; float fa, fb, fc, fd, wa, wb, wc, wd;
      tp_decode(tpa, ba, fa, wa); tp_decode(tpb, bb, fb, wb);
      tp_decode(tpc, bc, fc, wc); tp_decode(tpd, bd, fd, wd);
      float2 Fa = Ft2_1[ba*KDIM + lane]; float ga_ = gAr1[ra*KDIM + lane];
      float2 Fb = Ft2_1[bb*KDIM + lane]; float gb_ = gAr1[rb*KDIM + lane];
      float2 Fc = Ft2_1[bc*KDIM + lane]; float gc_ = gAr1[rc*KDIM + lane];
      float2 Fd = Ft2_1[bd*KDIM + lane]; float gd_ = gAr1[rd*KDIM + lane];
      acc0 += wa * (Fa.x + fa*(Fa.y - Fa.x)) * ga_;
      acc1 += wb * (Fb.x + fb*(Fb.y - Fb.x)) * gb_;
      acc2 += wc * (Fc.x + fc*(Fc.y - Fc.x)) * gc_;
      acc3 += wd * (Fd.x + fd*(Fd.y - Fd.x)) * gd_;
    }
    for (; i < m; i++){
      float tpa = __shfl(tp_l, i);
      int ra = __shfl(rcv_l, i);
      int ba; float fa, wa;
      tp_decode(tpa, ba, fa, wa);
      float2 Fa = Ft2_1[ba*KDIM + lane]; float ga_ = gAr1[ra*KDIM + lane];
      acc0 += wa * (Fa.x + fa*(Fa.y - Fa.x)) * ga_;
    }
  }
  lds[w][lane] = ((acc0 + acc1) + (acc2 + acc3));
  __syncthreads();
  float gfh = 0.f;
  for (int j = 0; j < KDIM; j++) gfh += lds[w][j] * WupT1[j*KDIM + lane];
  gF1[node*KDIM + lane] += gfh;
}

// merged: gr_over_r[e] = (sum_k gAr1*h1*dF1 + gAr0*h0*dF0) / r   (one wave per edge)
__global__ __launch_bounds__(256) void k_bwd_gr2(const int* ei, const float* tp_buf, const float* r_buf,
                                                 const float2* dF2_0, const float2* dF2_1,
                                                 const float* gAr0, const float* gAr1,
                                                 const float* h0, const float* h1,
                                                 float* gor){
  int tid = threadIdx.x;
  int w = tid>>6, lane = tid&63;
  int e = blockIdx.x*4 + w;
  float tp = tp_buf[e];
  int b; float fr, wm;
  tp_decode(tp, b, fr, wm);
  int snd = ei[e], rcv = ei[N_EDGES+e];
  float2 d1 = dF2_1[b*KDIM + lane];
  float2 d0 = dF2_0[b*KDIM + lane];
  float g1 = gAr1[rcv*KDIM + lane];
  float g0 = gAr0[rcv*KDIM + lane];
  float hv1 = h1[snd*KDIM + lane];
  float hv0 = h0[snd*KDIM + lane];
  float v = g1*hv1*(d1.x + fr*(d1.y - d1.x)) + g0*hv0*(d0.x + fr*(d0.y - d0.x));
  v = waveReduce(v) * wm;
  if (lane == 0) gor[e] = v / r_buf[e];
}

__global__ __launch_bounds__(256) void k_force(const int* ptr_r, const int* eid_r,
                                               const int* ptr_s, const int* eid_s,
                                               const float* gor,
                                               const float* vx, const float* vy, const float* vz,
                                               float* out_f){
  int tid = threadIdx.x; int w = tid>>6, lane = tid&63;
  int node = blockIdx.x*4 + w;
  float fx=0.f, fy=0.f, fz=0.f;
  int beg = ptr_r[node], end = ptr_r[node+1];
  for (int idx = beg + lane; idx < end; idx += 64){
    int e = eid_r[idx];
    float s = gor[e];
    fx -= s*vx[e]; fy -= s*vy[e]; fz -= s*vz[e];
  }
  beg = ptr_s[node]; end = ptr_s[node+1];
  for (int idx = beg + lane; idx < end; idx += 64){
    int e = eid_s[idx];
    float s = gor[e];
    fx += s*vx[e]; fy += s*vy[e]; fz += s*vz[e];
  }
  fx = waveReduce(fx); fy = waveReduce(fy); fz = waveReduce(fz);
  if (lane == 0){
    out_f[node*3+0] = fx; out_f[node*3+1] = fy; out_f[node*3+2] = fz;
  }
}

extern "C" void kernel_launch(void* const* d_in, const int* in_sizes, int n_in,
                              void* d_out, int out_size, void* d_ws, size_t ws_size,
                              hipStream_t stream){
  const float* pos    = (const float*)d_in[0];
  const float* attrs  = (const float*)d_in[1];
  const float* shifts = (const float*)d_in[2];
  const float* aE     = (const float*)d_in[3];
  const float* We     = (const float*)d_in[4];
  const float* Wup    = (const float*)d_in[5];
  const float* R1     = (const float*)d_in[6];
  const float* R2     = (const float*)d_in[7];
  const float* R3     = (const float*)d_in[8];
  const float* R4     = (const float*)d_in[9];
  const float* Wout   = (const float*)d_in[10];
  const float* Wsc    = (const float*)d_in[11];
  const float* theta  = (const float*)d_in[12];
  const float* Wmix   = (const float*)d_in[13];
  const float* w_read0= (const float*)d_in[14];
  const float* Wr1    = (const float*)d_in[15];
  const float* Wr2    = (const float*)d_in[16];
  const int*   ei     = (const int*)d_in[17];
  const int*   batch  = (const int*)d_in[18];

  char* base = (char*)d_ws;
  size_t off = 0;
  auto alloc = [&](size_t bytes)->void*{
    void* p = base + off;
    off = (off + bytes + 255) & ~(size_t)255;
    return p;
  };
  float* r_buf  = (float*)alloc(N_EDGES*sizeof(float));
  float* tp_buf = (float*)alloc(N_EDGES*sizeof(float));
  float* vx     = (float*)alloc(N_EDGES*sizeof(float));
  float* vy     = (float*)alloc(N_EDGES*sizeof(float));
  float* vz     = (float*)alloc(N_EDGES*sizeof(float));
  float* gor    = (float*)alloc(N_EDGES*sizeof(float));
  float* e_node = (float*)alloc(N_NODES*sizeof(float));
  float* h0     = (float*)alloc(N_NODES*KDIM*sizeof(float));
  float* feats1 = (float*)alloc(N_NODES*KDIM*sizeof(float));
  float* feats2 = (float*)alloc(N_NODES*KDIM*sizeof(float));
  float* h1     = (float*)alloc(N_NODES*KDIM*sizeof(float));
  float* sc1    = (float*)alloc(N_NODES*KDIM*sizeof(float));
  float* A00    = (float*)alloc(N_NODES*KDIM*sizeof(float));
  float* A01    = (float*)alloc(N_NODES*KDIM*sizeof(float));
  float* t_hid  = (float*)alloc(N_NODES*HIDR*sizeof(float));
  float* gF2    = (float*)alloc(N_NODES*KDIM*sizeof(float));
  float* gF1    = (float*)alloc(N_NODES*KDIM*sizeof(float));
  float* gAr1   = (float*)alloc(N_NODES*KDIM*sizeof(float));
  float* gAr0   = (float*)alloc(N_NODES*KDIM*sizeof(float));
  float2* Ft2_0 = (float2*)alloc((TBINS+1)*KDIM*sizeof(float2));
  float2* Ft2_1 = (float2*)alloc((TBINS+1)*KDIM*sizeof(float2));
  float2* dF2_0 = (float2*)alloc((TBINS+1)*KDIM*sizeof(float2));
  float2* dF2_1 = (float2*)alloc((TBINS+1)*KDIM*sizeof(float2));
  float* M0     = (float*)alloc(ZDIM*KDIM*sizeof(float));
  float* Msc0   = (float*)alloc(ZDIM*KDIM*sizeof(float));
  float* WoT0   = (float*)alloc(KDIM*KDIM*sizeof(float));
  float* WoT1   = (float*)alloc(KDIM*KDIM*sizeof(float));
  float* WmixT0 = (float*)alloc(KDIM*KDIM*sizeof(float));
  float* WmixT1 = (float*)alloc(KDIM*KDIM*sizeof(float));
  float* WupT1  = (float*)alloc(KDIM*KDIM*sizeof(float));
  float* WscT1  = (float*)alloc(ZDIM*KDIM*KDIM*sizeof(float));
  int* z_buf = (int*)alloc(N_NODES*sizeof(int));
  int* cnt_r = (int*)alloc(N_NODES*sizeof(int));
  int* cnt_s = (int*)alloc(N_NODES*sizeof(int));
  int* ptr_r = (int*)alloc((N_NODES+1)*sizeof(int));
  int* ptr_s = (int*)alloc((N_NODES+1)*sizeof(int));
  int* cur_r = (int*)alloc(N_NODES*sizeof(int));
  int* cur_s = (int*)alloc(N_NODES*sizeof(int));
  int* eid_r = (int*)alloc(N_EDGES*sizeof(int));
  int* eid_s = (int*)alloc(N_EDGES*sizeof(int));

  float* out_e = (float*)d_out;
  float* out_f = out_e + G_SEG;

  hipMemsetAsync(d_out, 0, (size_t)out_size*sizeof(float), stream);
  hipMemsetAsync(cnt_r, 0, N_NODES*sizeof(int), stream);
  hipMemsetAsync(cnt_s, 0, N_NODES*sizeof(int), stream);

  const int NB4 = N_NODES/4;
  const int EB  = N_EDGES/256;
  const int EB4 = N_EDGES/4;
  const int NBt = (N_NODES+255)/256;

  k_prep_dots<<<5,256,0,stream>>>(We, Wup, Wsc, M0, Msc0);
  k_prep_tr<<<240,256,0,stream>>>(Wup, Wsc, Wout, Wmix,
                                  WoT0, WoT1, WmixT0, WmixT1, WupT1, WscT1);
  k_node_init<<<NBt,256,0,stream>>>(attrs, aE, z_buf, e_node);
  k_h0<<<NB4,256,0,stream>>>(z_buf, M0, h0);
  k_edge_setup<<<EB,256,0,stream>>>(pos, shifts, ei, r_buf, tp_buf, vx, vy, vz, cnt_r, cnt_s);
  k_scan<<<1,1024,0,stream>>>(cnt_r, ptr_r, cur_r, cnt_s, ptr_s, cur_s);
  k_fill<<<EB,256,0,stream>>>(ei, cur_r, cur_s, eid_r, eid_s);
  k_table<<<TBINS+1,64,0,stream>>>(R1, R2, R3, R4, Ft2_0, Ft2_1, dF2_0, dF2_1);

  // ---- forward ----
  k_layer_fwd<<<NB4,256,0,stream>>>(0, z_buf, ptr_r, eid_r, ei, tp_buf, Ft2_0, h0,
      Wout, theta, Wmix, Msc0, sc1, w_read0, Wr1, Wr2,
      A00, feats1, t_hid, e_node);
  k_h1sc1<<<NB4,256,0,stream>>>(z_buf, feats1, Wup + KDIM*KDIM, Wsc + ZDIM*KDIM*KDIM, h1, sc1);
  k_layer_fwd<<<NB4,256,0,stream>>>(1, z_buf, ptr_r, eid_r, ei, tp_buf, Ft2_1, h1,
      Wout + 3*KDIM*KDIM, theta + 3*ZDIM*KDIM, Wmix + KDIM*KDIM, Msc0, sc1, w_read0, Wr1, Wr2,
      A01, feats2, t_hid, e_node);
  k_energy<<<NBt,256,0,stream>>>(e_node, batch, out_e);

  // ---- backward ----
  k_g2<<<NB4,256,0,stream>>>(t_hid, Wr1, Wr2, gF2);
  k_bwd_node<<<NB4,256,0,stream>>>(1, z_buf, gF2, A01, WmixT1, WoT1,
      theta + 3*ZDIM*KDIM, WscT1, w_read0, gAr1, gF1);
  k_bwd_gH<<<NB4,256,0,stream>>>(ptr_s, eid_s, ei, tp_buf, Ft2_1, gAr1, WupT1, gF1);
  k_bwd_node<<<NB4,256,0,stream>>>(0, z_buf, gF1, A00, WmixT0, WoT0,
      theta, WscT1, w_read0, gAr0, gF1);
  k_bwd_gr2<<<EB4,256,0,stream>>>(ei, tp_buf, r_buf, dF2_0, dF2_1, gAr0, gAr1, h0, h1, gor);
  k_force<<<NB4,256,0,stream>>>(ptr_r, eid_r, ptr_s, eid_s, gor, vx, vy, vz, out_f);
}

// Round 4
// 324.066 us; speedup vs baseline: 1.6970x; 1.0608x over previous
//
#include <hip/hip_runtime.h>
#include <math.h>

#define N_NODES 10000
#define N_EDGES 160000
#define G_SEG 16
#define ZDIM 10
#define KDIM 64
#define NBESS 8
#define HIDR 16
#define RMAXF 5.0f
#define AVG_NEI_F 16.0f
#define TBINS 1024

__device__ __forceinline__ float siluf(float x){ float s = 1.0f/(1.0f+expf(-x)); return x*s; }
__device__ __forceinline__ float dsiluf(float x){ float s = 1.0f/(1.0f+expf(-x)); return s*(1.0f + x*(1.0f-s)); }

__device__ __forceinline__ float waveReduce(float v){
  for (int off = 32; off > 0; off >>= 1) v += __shfl_down(v, off);
  return v;
}

__device__ __forceinline__ void tp_decode(float tp, int& b, float& fr, float& wm){
  float tpe = fmaxf(tp, 0.f);
  b = (int)tpe; if (b > TBINS-1) b = TBINS-1;
  fr = tpe - (float)b;
  wm = (tp >= 0.f) ? 1.f : 0.f;
}

// ---------------- parallel precompute ----------------
__global__ __launch_bounds__(256) void k_prep_dots(
    const float* We, const float* Wup, const float* Wsc,
    float* M0, float* Msc0){
  int idx = blockIdx.x*256 + threadIdx.x;
  if (idx >= 1280) return;
  int which = idx >= 640;
  int t = which ? idx - 640 : idx;
  int z = t >> 6, j = t & 63;
  float acc = 0.f;
  if (!which){
    #pragma unroll 8
    for (int k = 0; k < KDIM; k++) acc += We[z*KDIM + k] * Wup[k*KDIM + j];
    M0[z*KDIM + j] = acc;
  } else {
    #pragma unroll 8
    for (int k = 0; k < KDIM; k++) acc += We[z*KDIM + k] * Wsc[(z*KDIM + k)*KDIM + j];
    Msc0[z*KDIM + j] = acc;
  }
}

__global__ __launch_bounds__(256) void k_prep_tr(
    const float* Wup, const float* Wsc, const float* Wout, const float* Wmix,
    float* WoT0, float* WoT1, float* WmixT0, float* WmixT1,
    float* WupT1, float* WscT1){
  int t = blockIdx.x*256 + threadIdx.x;
  if (t < 20480){
    int arr = t >> 12;
    int rem = t & 4095;
    int j = rem >> 6, k = rem & 63;
    float v;
    float* dst;
    switch(arr){
      case 0: v = Wout[k*KDIM + j];                 dst = WoT0;   break;
      case 1: v = Wout[3*KDIM*KDIM + k*KDIM + j];   dst = WoT1;   break;
      case 2: v = Wmix[k*KDIM + j];                 dst = WmixT0; break;
      case 3: v = Wmix[KDIM*KDIM + k*KDIM + j];     dst = WmixT1; break;
      default:v = Wup[KDIM*KDIM + k*KDIM + j];      dst = WupT1;  break;
    }
    dst[rem] = v;
  } else {
    int idx2 = t - 20480;
    int z = idx2 >> 12;
    int rem = idx2 & 4095;
    int j = rem >> 6, k = rem & 63;
    WscT1[(z*KDIM + j)*KDIM + k] = Wsc[((ZDIM + z)*KDIM + k)*KDIM + j];
  }
}

__global__ __launch_bounds__(256) void k_node_init(const float* attrs, const float* aE,
                                                   int* z_buf, float* e_node){
  int n = blockIdx.x*256 + threadIdx.x;
  if (n >= N_NODES) return;
  int z = 0;
  for (int i = 1; i < ZDIM; i++) if (attrs[n*ZDIM+i] > 0.5f) z = i;
  z_buf[n] = z;
  e_node[n] = aE[z];
}

// edge geometry + table position + sender-z + CSR degree counting
__global__ __launch_bounds__(256) void k_edge_setup(const float* pos, const float* shifts, const int* ei,
                                                    const int* z_buf,
                                                    float* r_buf, float* tp_buf, int* ez,
                                                    float* vx, float* vy, float* vz,
                                                    int* cnt_r, int* cnt_s){
  int e = blockIdx.x*256 + threadIdx.x;
  int s = ei[e], rcv = ei[N_EDGES + e];
  float dx = pos[rcv*3+0] - pos[s*3+0] + shifts[e*3+0];
  float dy = pos[rcv*3+1] - pos[s*3+1] + shifts[e*3+1];
  float dz = pos[rcv*3+2] - pos[s*3+2] + shifts[e*3+2];
  float r = sqrtf(dx*dx + dy*dy + dz*dz + 1e-9f);
  r_buf[e] = r; vx[e] = dx; vy[e] = dy; vz[e] = dz;
  tp_buf[e] = (r < RMAXF) ? r * (TBINS / RMAXF) : -1.f;
  ez[e] = z_buf[s];
  atomicAdd(&cnt_s[s], 1);
  atomicAdd(&cnt_r[rcv], 1);
}

// two blocks: block 0 scans receiver counts, block 1 sender counts
__global__ __launch_bounds__(1024) void k_scan(const int* cnt_r, int* ptr_r, int* cur_r,
                                               const int* cnt_s, int* ptr_s, int* cur_s){
  __shared__ int part[1024];
  int tid = threadIdx.x;
  const int* cnt = blockIdx.x ? cnt_s : cnt_r;
  int* ptr = blockIdx.x ? ptr_s : ptr_r;
  int* cur = blockIdx.x ? cur_s : cur_r;
  const int per = 10;
  int start = tid*per;
  int s = 0;
  for (int t = 0; t < per; t++){ int i = start + t; if (i < N_NODES) s += cnt[i]; }
  part[tid] = s; __syncthreads();
  for (int d = 1; d < 1024; d <<= 1){
    int v = (tid >= d) ? part[tid-d] : 0;
    __syncthreads();
    part[tid] += v;
    __syncthreads();
  }
  int run = part[tid] - s;
  for (int t = 0; t < per; t++){
    int i = start + t;
    if (i < N_NODES){ ptr[i] = run; cur[i] = run; run += cnt[i]; }
  }
  if (tid == 1023) ptr[N_NODES] = part[1023];
}

__global__ __launch_bounds__(256) void k_fill(const int* ei, int* cur_r, int* cur_s,
                                              int* eid_r, int* eid_s){
  int e = blockIdx.x*256 + threadIdx.x;
  int p = atomicAdd(&cur_s[ei[e]], 1); eid_s[p] = e;
  int p2 = atomicAdd(&cur_r[ei[N_EDGES + e]], 1); eid_r[p2] = e;
}

// ---------------- radial-MLP tables, packed float2 ----------------
__global__ __launch_bounds__(64) void k_table(const float* R1g, const float* R2g,
                                              const float* R3g, const float* R4g,
                                              float2* Ft2_0, float2* Ft2_1,
                                              float2* dF2_0, float2* dF2_1){
  int t = blockIdx.x, j = threadIdx.x;
  __shared__ float efs[NBESS], defs[NBESS];
  __shared__ float xs[KDIM], dxs[KDIM];
  if (j < NBESS){
    double r = (double)t * (double)RMAXF / (double)TBINS;
    double w = (double)(j+1) * M_PI / (double)RMAXF;
    double c = sqrt(2.0 / (double)RMAXF);
    double bess, dbess;
    if (r < 1e-12){ bess = c*w; dbess = 0.0; }
    else {
      double sw = sin(w*r), cw = cos(w*r);
      bess = c*sw/r;
      dbess = c*(w*cw*r - sw)/(r*r);
    }
    double xx = r / (double)RMAXF;
    double f = 0.0, df = 0.0;
    if (xx < 1.0){
      double x2 = xx*xx, x4 = x2*x2, x5 = x4*xx, x6 = x5*xx, x7 = x6*xx;
      f = 1.0 - 21.0*x5 + 35.0*x6 - 15.0*x7;
      df = (-105.0*x4 + 210.0*x5 - 105.0*x6) / (double)RMAXF;
    }
    efs[j]  = (float)(bess*f);
    defs[j] = (float)(dbess*f + bess*df);
  }
  __syncthreads();
  for (int i = 0; i < 2; i++){
    const float* R1 = R1g + i*NBESS*KDIM;
    const float* R2 = R2g + i*KDIM*KDIM;
    const float* R3 = R3g + i*KDIM*KDIM;
    const float* R4 = R4g + i*KDIM*KDIM;
    float z = 0.f, dz = 0.f;
    for (int b = 0; b < NBESS; b++){ float w = R1[b*KDIM+j]; z += efs[b]*w; dz += defs[b]*w; }
    float v = siluf(z), dv = dsiluf(z)*dz;
    xs[j] = v; dxs[j] = dv; __syncthreads();
    z = 0.f; dz = 0.f;
    for (int k = 0; k < KDIM; k++){ float w = R2[k*KDIM+j]; z += xs[k]*w; dz += dxs[k]*w; }
    v = siluf(z); dv = dsiluf(z)*dz; __syncthreads();
    xs[j] = v; dxs[j] = dv; __syncthreads();
    z = 0.f; dz = 0.f;
    for (int k = 0; k < KDIM; k++){ float w = R3[k*KDIM+j]; z += xs[k]*w; dz += dxs[k]*w; }
    v = siluf(z); dv = dsiluf(z)*dz; __syncthreads();
    xs[j] = v; dxs[j] = dv; __syncthreads();
    z = 0.f; dz = 0.f;
    for (int k = 0; k < KDIM; k++){ float w = R4[k*KDIM+j]; z += xs[k]*w; dz += dxs[k]*w; }
    float2* Ft  = i ? Ft2_1 : Ft2_0;
    float2* dFt = i ? dF2_1 : dF2_0;
    Ft[t*KDIM+j].x = z;  if (t > 0) Ft[(t-1)*KDIM+j].y = z;
    dFt[t*KDIM+j].x = dz; if (t > 0) dFt[(t-1)*KDIM+j].y = dz;
    __syncthreads();
  }
}

// ---------------- layer-0 forward: M0-table gather + full node epilogue + h1/sc1 ----------------
__global__ __launch_bounds__(256) void k_layer0_fwd(
    const int* z_buf, const int* ptr_r, const int* eid_r,
    const float* tp_buf, const int* ez, const float2* Ft2, const float* M0,
    const float* Wout0, const float* theta0, const float* Wmix0,
    const float* Msc0, const float* w_read0,
    const float* Wup1, const float* Wsc1,
    float* A0_out, float* h1, float* sc1, float* e_node){
  __shared__ float lds[4][KDIM];
  int tid = threadIdx.x;
  int w = tid >> 6, lane = tid & 63;
  int node = blockIdx.x*4 + w;
  int z = z_buf[node];
  int beg = ptr_r[node], end = ptr_r[node+1];
  int deg = end - beg;
  float acc0 = 0.f, acc1 = 0.f, acc2 = 0.f, acc3 = 0.f;
  for (int base = 0; base < deg; base += 64){
    int m = min(64, deg - base);
    float tp_l = -1.f; int sz_l = 0;
    if (lane < m){
      int e = eid_r[beg + base + lane];
      tp_l = tp_buf[e];
      sz_l = ez[e];
    }
    int i = 0;
    for (; i + 4 <= m; i += 4){
      float tpa = __shfl(tp_l, i),   tpb = __shfl(tp_l, i+1);
      float tpc = __shfl(tp_l, i+2), tpd = __shfl(tp_l, i+3);
      int za = __shfl(sz_l, i),   zb = __shfl(sz_l, i+1);
      int zc = __shfl(sz_l, i+2), zd = __shfl(sz_l, i+3);
      int ba, bb, bc, bd; float fa, fb, fc, fd, wa, wb, wc, wd;
      tp_decode(tpa, ba, fa, wa); tp_decode(tpb, bb, fb, wb);
      tp_decode(tpc, bc, fc, wc); tp_decode(tpd, bd, fd, wd);
      float2 Fa = Ft2[ba*KDIM + lane]; float ha = M0[za*KDIM + lane];
      float2 Fb = Ft2[bb*KDIM + lane]; float hb = M0[zb*KDIM + lane];
      float2 Fc = Ft2[bc*KDIM + lane]; float hc = M0[zc*KDIM + lane];
      float2 Fd = Ft2[bd*KDIM + lane]; float hd = M0[zd*KDIM + lane];
      acc0 += wa * (Fa.x + fa*(Fa.y - Fa.x)) * ha;
      acc1 += wb * (Fb.x + fb*(Fb.y - Fb.x)) * hb;
      acc2 += wc * (Fc.x + fc*(Fc.y - Fc.x)) * hc;
      acc3 += wd * (Fd.x + fd*(Fd.y - Fd.x)) * hd;
    }
    for (; i < m; i++){
      float tpa = __shfl(tp_l, i);
      int za = __shfl(sz_l, i);
      int ba; float fa, wa;
      tp_decode(tpa, ba, fa, wa);
      float2 Fa = Ft2[ba*KDIM + lane]; float ha = M0[za*KDIM + lane];
      acc0 += wa * (Fa.x + fa*(Fa.y - Fa.x)) * ha;
    }
  }
  float acc = ((acc0 + acc1) + (acc2 + acc3)) * (1.0f/AVG_NEI_F);
  lds[w][lane] = acc;
  __syncthreads();
  float a0 = 0.f;
  for (int k = 0; k < KDIM; k++) a0 += lds[w][k] * Wout0[k*KDIM + lane];
  A0_out[node*KDIM + lane] = a0;
  float t0 = theta0[(0*ZDIM + z)*KDIM + lane];
  float t1 = theta0[(1*ZDIM + z)*KDIM + lane];
  float t2 = theta0[(2*ZDIM + z)*KDIM + lane];
  float q = t0 + t1*a0 + t2*a0*a0;
  __syncthreads();
  lds[w][lane] = q*a0;
  __syncthreads();
  float f = 0.f;
  for (int k = 0; k < KDIM; k++) f += lds[w][k] * Wmix0[k*KDIM + lane];
  f += Msc0[z*KDIM + lane];
  float p = f * w_read0[lane];
  p = waveReduce(p);
  if (lane == 0) e_node[node] += p;
  __syncthreads();
  lds[w][lane] = f;
  __syncthreads();
  float h = 0.f, s = 0.f;
  for (int k = 0; k < KDIM; k++){
    float fv = lds[w][k];
    h += fv * Wup1[k*KDIM + lane];
    s += fv * Wsc1[(z*KDIM + k)*KDIM + lane];
  }
  h1[node*KDIM + lane] = h;
  sc1[node*KDIM + lane] = s;
}

// ---------------- layer-1 forward ----------------
__global__ __launch_bounds__(256) void k_layer1_fwd(
    const int* z_buf, const int* ptr_r, const int* eid_r, const int* ei,
    const float* tp_buf, const float2* Ft2, const float* h1,
    const float* Wout1, const float* theta1, const float* Wmix1,
    const float* sc1, const float* Wr1, const float* Wr2,
    float* A0_out, float* t_hid, float* e_node){
  __shared__ float lds[4][KDIM];
  int tid = threadIdx.x;
  int w = tid >> 6, lane = tid & 63;
  int node = blockIdx.x*4 + w;
  int beg = ptr_r[node], end = ptr_r[node+1];
  int deg = end - beg;
  float acc0 = 0.f, acc1 = 0.f, acc2 = 0.f, acc3 = 0.f;
  for (int base = 0; base < deg; base += 64){
    int m = min(64, deg - base);
    float tp_l = -1.f; int snd_l = 0;
    if (lane < m){
      int e = eid_r[beg + base + lane];
      tp_l = tp_buf[e];
      snd_l = ei[e];
    }
    int i = 0;
    for (; i + 4 <= m; i += 4){
      float tpa = __shfl(tp_l, i),   tpb = __shfl(tp_l, i+1);
      float tpc = __shfl(tp_l, i+2), tpd = __shfl(tp_l, i+3);
      int sa = __shfl(snd_l, i),   sb = __shfl(snd_l, i+1);
      int sc = __shfl(snd_l, i+2), sd = __shfl(snd_l, i+3);
      int ba, bb, bc, bd; float fa, fb, fc, fd, wa, wb, wc, wd;
      tp_decode(tpa, ba, fa, wa); tp_decode(tpb, bb, fb, wb);
      tp_decode(tpc, bc, fc, wc); tp_decode(tpd, bd, fd, wd);
      float2 Fa = Ft2[ba*KDIM + lane]; float ha = h1[sa*KDIM + lane];
      float2 Fb = Ft2[bb*KDIM + lane]; float hb = h1[sb*KDIM + lane];
      float2 Fc = Ft2[bc*KDIM + lane]; float hc = h1[sc*KDIM + lane];
      float2 Fd = Ft2[bd*KDIM + lane]; float hd = h1[sd*KDIM + lane];
      acc0 += wa * (Fa.x + fa*(Fa.y - Fa.x)) * ha;
      acc1 += wb * (Fb.x + fb*(Fb.y - Fb.x)) * hb;
      acc2 += wc * (Fc.x + fc*(Fc.y - Fc.x)) * hc;
      acc3 += wd * (Fd.x + fd*(Fd.y - Fd.x)) * hd;
    }
    for (; i < m; i++){
      float tpa = __shfl(tp_l, i);
      int sa = __shfl(snd_l, i);
      int ba; float fa, wa;
      tp_decode(tpa, ba, fa, wa);
      float2 Fa = Ft2[ba*KDIM + lane]; float ha = h1[sa*KDIM + lane];
      acc0 += wa * (Fa.x + fa*(Fa.y - Fa.x)) * ha;
    }
  }
  float acc = ((acc0 + acc1) + (acc2 + acc3)) * (1.0f/AVG_NEI_F);
  int z = z_buf[node];
  lds[w][lane] = acc;
  __syncthreads();
  float a0 = 0.f;
  for (int k = 0; k < KDIM; k++) a0 += lds[w][k] * Wout1[k*KDIM + lane];
  A0_out[node*KDIM + lane] = a0;
  float t0 = theta1[(0*ZDIM + z)*KDIM + lane];
  float t1 = theta1[(1*ZDIM + z)*KDIM + lane];
  float t2 = theta1[(2*ZDIM + z)*KDIM + lane];
  float q = t0 + t1*a0 + t2*a0*a0;
  __syncthreads();
  lds[w][lane] = q*a0;
  __syncthreads();
  float f = 0.f;
  for (int k = 0; k < KDIM; k++) f += lds[w][k] * Wmix1[k*KDIM + lane];
  f += sc1[node*KDIM + lane];
  __syncthreads();
  lds[w][lane] = f;
  __syncthreads();
  int hh = lane & 15;
  int quad = lane >> 4;
  float tpart = 0.f;
  for (int jj = quad*16; jj < quad*16+16; jj++)
    tpart += lds[w][jj] * Wr1[jj*HIDR + hh];
  tpart += __shfl_xor(tpart, 16);
  tpart += __shfl_xor(tpart, 32);
  if (lane < 16) t_hid[node*HIDR + hh] = tpart;
  float ne = siluf(tpart) * Wr2[hh];
  ne = waveReduce(ne);
  if (lane == 0) e_node[node] += 0.25f * ne;
}

__global__ __launch_bounds__(256) void k_energy(const float* e_node, const int* batch, float* out_e){
  __shared__ float part[G_SEG];
  int tid = threadIdx.x;
  if (tid < G_SEG) part[tid] = 0.f;
  __syncthreads();
  int n = blockIdx.x*256 + tid;
  if (n < N_NODES) atomicAdd(&part[batch[n]], e_node[n]);
  __syncthreads();
  if (tid < G_SEG) atomicAdd(&out_e[tid], part[tid]);
}

// ---------------- bwd layer-1 node: gF2 (inline) -> gAr1, gF1 ----------------
__global__ __launch_bounds__(256) void k_bwd1(
    const int* z_buf, const float* t_hid, const float* Wr1, const float* Wr2,
    const float* A01, const float* WmixT1, const float* WoT1, const float* theta1,
    const float* WscT1, const float* w_read0,
    float* gAr1, float* gF1){
  __shared__ float ga[4][KDIM];
  __shared__ float gb[4][KDIM];
  int tid = threadIdx.x; int w = tid>>6, lane = tid&63;
  int node = blockIdx.x*4 + w;
  int hh = lane & 15;
  float tv = t_hid[node*HIDR + hh];
  float coeff = dsiluf(tv) * Wr2[hh];   // valid in lanes 0..15 (replicated)
  float g = 0.f;
  #pragma unroll
  for (int h2 = 0; h2 < HIDR; h2++){
    float c = __shfl(coeff, h2);
    g += c * Wr1[lane*HIDR + h2];
  }
  ga[w][lane] = g;
  __syncthreads();
  float gP = 0.f;
  for (int j = 0; j < KDIM; j++) gP += ga[w][j] * WmixT1[j*KDIM + lane];
  int z = z_buf[node];
  float a = A01[node*KDIM + lane];
  float t0 = theta1[(0*ZDIM+z)*KDIM + lane];
  float t1 = theta1[(1*ZDIM+z)*KDIM + lane];
  float t2 = theta1[(2*ZDIM+z)*KDIM + lane];
  float u = t0 + 2.f*t1*a + 3.f*t2*a*a;
  gb[w][lane] = gP * u;
  __syncthreads();
  float gAr = 0.f;
  for (int j = 0; j < KDIM; j++) gAr += gb[w][j] * WoT1[j*KDIM + lane];
  gAr1[node*KDIM + lane] = gAr * (1.0f/AVG_NEI_F);
  float gsc = 0.f;
  for (int j = 0; j < KDIM; j++) gsc += ga[w][j] * WscT1[(z*KDIM + j)*KDIM + lane];
  gF1[node*KDIM + lane] = w_read0[lane] + gsc;
}

// ---------------- bwd: sender-gather gH + layer-0 node bwd -> gAr0 ----------------
__global__ __launch_bounds__(256) void k_bwd_gH0(
    const int* z_buf, const int* ptr_s, const int* eid_s, const int* ei,
    const float* tp_buf, const float2* Ft2_1,
    const float* gAr1, const float* WupT1, const float* gF1,
    const float* A00, const float* WmixT0, const float* WoT0, const float* theta0,
    float* gAr0){
  __shared__ float ga[4][KDIM];
  __shared__ float gb[4][KDIM];
  int tid = threadIdx.x; int w = tid>>6, lane = tid&63;
  int node = blockIdx.x*4 + w;
  int beg = ptr_s[node], end = ptr_s[node+1];
  int deg = end - beg;
  float acc0 = 0.f, acc1 = 0.f, acc2 = 0.f, acc3 = 0.f;
  for (int base = 0; base < deg; base += 64){
    int m = min(64, deg - base);
    float tp_l = -1.f; int rcv_l = 0;
    if (lane < m){
      int e = eid_s[beg + base + lane];
      tp_l = tp_buf[e];
      rcv_l = ei[N_EDGES + e];
    }
    int i = 0;
    for (; i + 4 <= m; i += 4){
      float tpa = __shfl(tp_l, i),   tpb = __shfl(tp_l, i+1);
      float tpc = __shfl(tp_l, i+2), tpd = __shfl(tp_l, i+3);
      int ra = __shfl(rcv_l, i),   rb = __shfl(rcv_l, i+1);
      int rc = __shfl(rcv_l, i+2), rd = __shfl(rcv_l, i+3);
      int ba, bb, bc, bd; float fa, fb, fc, fd, wa, wb, wc, wd;
      tp_decode(tpa, ba, fa, wa); tp_decode(tpb, bb, fb, wb);
      tp_decode(tpc, bc, fc, wc); tp_decode(tpd, bd, fd, wd);
      float2 Fa = Ft2_1[ba*KDIM + lane]; float ga_ = gAr1[ra*KDIM + lane];
      float2 Fb = Ft2_1[bb*KDIM + lane]; float gb_ = gAr1[rb*KDIM + lane];
      float2 Fc = Ft2_1[bc*KDIM + lane]; float gc_ = gAr1[rc*KDIM + lane];
      float2 Fd = Ft2_1[bd*KDIM + lane]; float gd_ = gAr1[rd*KDIM + lane];
      acc0 += wa * (Fa.x + fa*(Fa.y - Fa.x)) * ga_;
      acc1 += wb * (Fb.x + fb*(Fb.y - Fb.x)) * gb_;
      acc2 += wc * (Fc.x + fc*(Fc.y - Fc.x)) * gc_;
      acc3 += wd * (Fd.x + fd*(Fd.y - Fd.x)) * gd_;
    }
    for (; i < m; i++){
      float tpa = __shfl(tp_l, i);
      int ra = __shfl(rcv_l, i);
      int ba; float fa, wa;
      tp_decode(tpa, ba, fa, wa);
      float2 Fa = Ft2_1[ba*KDIM + lane]; float ga_ = gAr1[ra*KDIM + lane];
      acc0 += wa * (Fa.x + fa*(Fa.y - Fa.x)) * ga_;
    }
  }
  ga[w][lane] = ((acc0 + acc1) + (acc2 + acc3));
  __syncthreads();
  float gfh = 0.f;
  for (int j = 0; j < KDIM; j++) gfh += ga[w][j] * WupT1[j*KDIM + lane];
  float gtot = gF1[node*KDIM + lane] + gfh;
  gb[w][lane] = gtot;
  __syncthreads();
  float gP = 0.f;
  for (int j = 0; j < KDIM; j++) gP += gb[w][j] * WmixT0[j*KDIM + lane];
  int z = z_buf[node];
  float a = A00[node*KDIM + lane];
  float t0 = theta0[(0*ZDIM+z)*KDIM + lane];
  float t1 = theta0[(1*ZDIM+z)*KDIM + lane];
  float t2 = theta0[(2*ZDIM+z)*KDIM + lane];
  float u = t0 + 2.f*t1*a + 3.f*t2*a*a;
  __syncthreads();
  ga[w][lane] = gP * u;
  __syncthreads();
  float gAr = 0.f;
  for (int j = 0; j < KDIM; j++) gAr += ga[w][j] * WoT0[j*KDIM + lane];
  gAr0[node*KDIM + lane] = gAr * (1.0f/AVG_NEI_F);
}

// merged per-edge gr/r (layer0 h from M0 table via ez)
__global__ __launch_bounds__(256) void k_bwd_gr2(const int* ei, const float* tp_buf, const float* r_buf,
                                                 const int* ez, const float* M0,
                                                 const float2* dF2_0, const float2* dF2_1,
                                                 const float* gAr0, const float* gAr1,
                                                 const float* h1,
                                                 float* gor){
  int tid = threadIdx.x;
  int w = tid>>6, lane = tid&63;
  int e = blockIdx.x*4 + w;
  float tp = tp_buf[e];
  int b; float fr, wm;
  tp_decode(tp, b, fr, wm);
  int snd = ei[e], rcv = ei[N_EDGES+e];
  float2 d1 = dF2_1[b*KDIM + lane];
  float2 d0 = dF2_0[b*KDIM + lane];
  float g1 = gAr1[rcv*KDIM + lane];
  float g0 = gAr0[rcv*KDIM + lane];
  float hv1 = h1[snd*KDIM + lane];
  float hv0 = M0[ez[e]*KDIM + lane];
  float v = g1*hv1*(d1.x + fr*(d1.y - d1.x)) + g0*hv0*(d0.x + fr*(d0.y - d0.x));
  v = waveReduce(v) * wm;
  if (lane == 0) gor[e] = v / r_buf[e];
}

__global__ __launch_bounds__(256) void k_force(const int* ptr_r, const int* eid_r,
                                               const int* ptr_s, const int* eid_s,
                                               const float* gor,
                                               const float* vx, const float* vy, const float* vz,
                                               float* out_f){
  int tid = threadIdx.x; int w = tid>>6, lane = tid&63;
  int node = blockIdx.x*4 + w;
  float fx=0.f, fy=0.f, fz=0.f;
  int beg = ptr_r[node], end = ptr_r[node+1];
  for (int idx = beg + lane; idx < end; idx += 64){
    int e = eid_r[idx];
    float s = gor[e];
    fx -= s*vx[e]; fy -= s*vy[e]; fz -= s*vz[e];
  }
  beg = ptr_s[node]; end = ptr_s[node+1];
  for (int idx = beg + lane; idx < end; idx += 64){
    int e = eid_s[idx];
    float s = gor[e];
    fx += s*vx[e]; fy += s*vy[e]; fz += s*vz[e];
  }
  fx = waveReduce(fx); fy = waveReduce(fy); fz = waveReduce(fz);
  if (lane == 0){
    out_f[node*3+0] = fx; out_f[node*3+1] = fy; out_f[node*3+2] = fz;
  }
}

extern "C" void kernel_launch(void* const* d_in, const int* in_sizes, int n_in,
                              void* d_out, int out_size, void* d_ws, size_t ws_size,
                              hipStream_t stream){
  const float* pos    = (const float*)d_in[0];
  const float* attrs  = (const float*)d_in[1];
  const float* shifts = (const float*)d_in[2];
  const float* aE     = (const float*)d_in[3];
  const float* We     = (const float*)d_in[4];
  const float* Wup    = (const float*)d_in[5];
  const float* R1     = (const float*)d_in[6];
  const float* R2     = (const float*)d_in[7];
  const float* R3     = (const float*)d_in[8];
  const float* R4     = (const float*)d_in[9];
  const float* Wout   = (const float*)d_in[10];
  const float* Wsc    = (const float*)d_in[11];
  const float* theta  = (const float*)d_in[12];
  const float* Wmix   = (const float*)d_in[13];
  const float* w_read0= (const float*)d_in[14];
  const float* Wr1    = (const float*)d_in[15];
  const float* Wr2    = (const float*)d_in[16];
  const int*   ei     = (const int*)d_in[17];
  const int*   batch  = (const int*)d_in[18];

  char* base = (char*)d_ws;
  size_t off = 0;
  auto alloc = [&](size_t bytes)->void*{
    void* p = base + off;
    off = (off + bytes + 255) & ~(size_t)255;
    return p;
  };
  float* r_buf  = (float*)alloc(N_EDGES*sizeof(float));
  float* tp_buf = (float*)alloc(N_EDGES*sizeof(float));
  float* vx     = (float*)alloc(N_EDGES*sizeof(float));
  float* vy     = (float*)alloc(N_EDGES*sizeof(float));
  float* vz     = (float*)alloc(N_EDGES*sizeof(float));
  float* gor    = (float*)alloc(N_EDGES*sizeof(float));
  int*   ez     = (int*)alloc(N_EDGES*sizeof(int));
  float* e_node = (float*)alloc(N_NODES*sizeof(float));
  float* h1     = (float*)alloc(N_NODES*KDIM*sizeof(float));
  float* sc1    = (float*)alloc(N_NODES*KDIM*sizeof(float));
  float* A00    = (float*)alloc(N_NODES*KDIM*sizeof(float));
  float* A01    = (float*)alloc(N_NODES*KDIM*sizeof(float));
  float* t_hid  = (float*)alloc(N_NODES*HIDR*sizeof(float));
  float* gF1    = (float*)alloc(N_NODES*KDIM*sizeof(float));
  float* gAr1   = (float*)alloc(N_NODES*KDIM*sizeof(float));
  float* gAr0   = (float*)alloc(N_NODES*KDIM*sizeof(float));
  float2* Ft2_0 = (float2*)alloc((TBINS+1)*KDIM*sizeof(float2));
  float2* Ft2_1 = (float2*)alloc((TBINS+1)*KDIM*sizeof(float2));
  float2* dF2_0 = (float2*)alloc((TBINS+1)*KDIM*sizeof(float2));
  float2* dF2_1 = (float2*)alloc((TBINS+1)*KDIM*sizeof(float2));
  float* M0     = (float*)alloc(ZDIM*KDIM*sizeof(float));
  float* Msc0   = (float*)alloc(ZDIM*KDIM*sizeof(float));
  float* WoT0   = (float*)alloc(KDIM*KDIM*sizeof(float));
  float* WoT1   = (float*)alloc(KDIM*KDIM*sizeof(float));
  float* WmixT0 = (float*)alloc(KDIM*KDIM*sizeof(float));
  float* WmixT1 = (float*)alloc(KDIM*KDIM*sizeof(float));
  float* WupT1  = (float*)alloc(KDIM*KDIM*sizeof(float));
  float* WscT1  = (float*)alloc(ZDIM*KDIM*KDIM*sizeof(float));
  int* z_buf = (int*)alloc(N_NODES*sizeof(int));
  int* cnt_r = (int*)alloc(N_NODES*sizeof(int));
  int* cnt_s = (int*)alloc(N_NODES*sizeof(int));
  int* ptr_r = (int*)alloc((N_NODES+1)*sizeof(int));
  int* ptr_s = (int*)alloc((N_NODES+1)*sizeof(int));
  int* cur_r = (int*)alloc(N_NODES*sizeof(int));
  int* cur_s = (int*)alloc(N_NODES*sizeof(int));
  int* eid_r = (int*)alloc(N_EDGES*sizeof(int));
  int* eid_s = (int*)alloc(N_EDGES*sizeof(int));

  float* out_e = (float*)d_out;
  float* out_f = out_e + G_SEG;

  hipMemsetAsync(d_out, 0, (size_t)out_size*sizeof(float), stream);
  hipMemsetAsync(cnt_r, 0, N_NODES*sizeof(int), stream);
  hipMemsetAsync(cnt_s, 0, N_NODES*sizeof(int), stream);

  const int NB4 = N_NODES/4;
  const int EB  = N_EDGES/256;
  const int EB4 = N_EDGES/4;
  const int NBt = (N_NODES+255)/256;

  const float* Wup1 = Wup + KDIM*KDIM;
  const float* Wsc1 = Wsc + ZDIM*KDIM*KDIM;
  const float* Wout1 = Wout + 3*KDIM*KDIM;
  const float* theta1 = theta + 3*ZDIM*KDIM;
  const float* Wmix1 = Wmix + KDIM*KDIM;

  k_prep_dots<<<5,256,0,stream>>>(We, Wup, Wsc, M0, Msc0);
  k_prep_tr<<<240,256,0,stream>>>(Wup, Wsc, Wout, Wmix,
                                  WoT0, WoT1, WmixT0, WmixT1, WupT1, WscT1);
  k_node_init<<<NBt,256,0,stream>>>(attrs, aE, z_buf, e_node);
  k_edge_setup<<<EB,256,0,stream>>>(pos, shifts, ei, z_buf, r_buf, tp_buf, ez, vx, vy, vz, cnt_r, cnt_s);
  k_scan<<<2,1024,0,stream>>>(cnt_r, ptr_r, cur_r, cnt_s, ptr_s, cur_s);
  k_fill<<<EB,256,0,stream>>>(ei, cur_r, cur_s, eid_r, eid_s);
  k_table<<<TBINS+1,64,0,stream>>>(R1, R2, R3, R4, Ft2_0, Ft2_1, dF2_0, dF2_1);

  // ---- forward ----
  k_layer0_fwd<<<NB4,256,0,stream>>>(z_buf, ptr_r, eid_r, tp_buf, ez, Ft2_0, M0,
      Wout, theta, Wmix, Msc0, w_read0, Wup1, Wsc1,
      A00, h1, sc1, e_node);
  k_layer1_fwd<<<NB4,256,0,stream>>>(z_buf, ptr_r, eid_r, ei, tp_buf, Ft2_1, h1,
      Wout1, theta1, Wmix1, sc1, Wr1, Wr2,
      A01, t_hid, e_node);
  k_energy<<<NBt,256,0,stream>>>(e_node, batch, out_e);

  // ---- backward ----
  k_bwd1<<<NB4,256,0,stream>>>(z_buf, t_hid, Wr1, Wr2, A01, WmixT1, WoT1, theta1,
      WscT1, w_read0, gAr1, gF1);
  k_bwd_gH0<<<NB4,256,0,stream>>>(z_buf, ptr_s, eid_s, ei, tp_buf, Ft2_1,
      gAr1, WupT1, gF1, A00, WmixT0, WoT0, theta, gAr0);
  k_bwd_gr2<<<EB4,256,0,stream>>>(ei, tp_buf, r_buf, ez, M0, dF2_0, dF2_1, gAr0, gAr1, h1, gor);
  k_force<<<NB4,256,0,stream>>>(ptr_r, eid_r, ptr_s, eid_s, gor, vx, vy, vz, out_f);
}